// Round 4
// baseline (2057.438 us; speedup 1.0000x reference)
//
#include <hip/hip_runtime.h>
#include <hip/hip_bf16.h>

#define MUL 32
#define F4 128
#define NB 10
#define NH 100
#define EROW 136   // LDS row stride (ushorts) for sHW/sFeat: 272 B = 17*16, 16B-aligned rows
#define REC 40     // bytes per sorted edge record: src int @0, ele bf16[10] @4, ea f32[4] @24

#define INV_SQRT32 0.17677669529663687f
#define INV_SQRT10 0.31622776601683794f
#define INV_SQRT100 0.1f
#define INV_SQRT3 0.5773502691896258f
#define AGG_SCALE 0.25f   // 1/sqrt(16)
#define INV8 0.125f       // 1/sqrt(64)
#define C_S 0.3826834323650898f
#define C_X 0.9238795325112867f

typedef __attribute__((ext_vector_type(8))) short short8;
typedef __attribute__((ext_vector_type(4))) float float4v;

__device__ __forceinline__ float bf2f(__hip_bfloat16 v) { return __bfloat162float(v); }
__device__ __forceinline__ unsigned short f2b(float x) {
    __hip_bfloat16 b = __float2bfloat16(x);
    return *(unsigned short*)&b;
}
__device__ __forceinline__ float b2f(unsigned short u) {
    __hip_bfloat16 b;
    *(unsigned short*)&b = u;
    return __bfloat162float(b);
}
// flag: 1 = inputs fp32, 0 = inputs bf16
__device__ __forceinline__ float ldin(const void* p, size_t i, int f) {
    return f ? ((const float*)p)[i] : bf2f(((const __hip_bfloat16*)p)[i]);
}

// ---------------------------------------------------------------------------
__global__ void detect_dtype_kernel(const void* __restrict__ node_attr, int* __restrict__ flag) {
    unsigned w = *(const unsigned*)node_attr;
    *flag = (w == 0x3F800000u) ? 1 : 0;
}

// ---------------------------------------------------------------------------
// prep: k-contiguous bf16 B-operands.
// ---------------------------------------------------------------------------
__global__ __launch_bounds__(256) void prep_kernel(
    const void* __restrict__ Wfc1,   // 10 x 100
    const void* __restrict__ Wfc2,   // 100 x 128
    const void* __restrict__ Wl20,   // 64 x 32
    const void* __restrict__ Wl21,   // 64 x 32
    const int* __restrict__ flagp,
    unsigned short* __restrict__ w1t,
    unsigned short* __restrict__ w2t,
    unsigned short* __restrict__ w20t,
    unsigned short* __restrict__ w21t)
{
    int f = *flagp;
    int t = threadIdx.x;
    for (int i = t; i < 128 * 128; i += 256) {
        int n = i >> 7, k = i & 127;
        w2t[i] = (k < NH) ? f2b(ldin(Wfc2, (size_t)k * 128 + n, f)) : 0;
    }
    for (int i = t; i < 32 * 64; i += 256) {
        int v = i >> 6, u = i & 63;
        w20t[i] = f2b(ldin(Wl20, (size_t)u * 32 + v, f));
        w21t[i] = f2b(ldin(Wl21, (size_t)u * 32 + v, f));
    }
    for (int i = t; i < 112 * 32; i += 256) {
        int n = i >> 5, k = i & 31;
        w1t[i] = (k < NB && n < NH) ? f2b(ldin(Wfc1, (size_t)k * NH + n, f)) : 0;
    }
}

// ---------------------------------------------------------------------------
// Counting sort of edges by dst: hist -> scan -> scatter_build.
// After scatter_build, cnt[n] = END offset of bucket n (== start of bucket n+1).
// ---------------------------------------------------------------------------
__global__ __launch_bounds__(256) void hist_kernel(
    const int* __restrict__ edst, int* __restrict__ cnt, int E)
{
    int i = blockIdx.x * 256 + threadIdx.x;
    if (i < E) atomicAdd(&cnt[edst[i]], 1);
}

__global__ __launch_bounds__(1024) void scan_kernel(int* __restrict__ cnt, int N)
{
    __shared__ int wsum[16];
    __shared__ int carry;
    int t = threadIdx.x, lane = t & 63, wid = t >> 6;
    if (t == 0) carry = 0;
    __syncthreads();
    for (int c0 = 0; c0 < N; c0 += 1024) {
        int i = c0 + t;
        int v = (i < N) ? cnt[i] : 0;
        int x = v;
#pragma unroll
        for (int d = 1; d < 64; d <<= 1) { int yv = __shfl_up(x, d); if (lane >= d) x += yv; }
        if (lane == 63) wsum[wid] = x;
        __syncthreads();
        if (wid == 0 && lane < 16) {
            int s = wsum[lane];
#pragma unroll
            for (int d = 1; d < 16; d <<= 1) { int yv = __shfl_up(s, d); if (lane >= d) s += yv; }
            wsum[lane] = s;
        }
        __syncthreads();
        int pre = (wid > 0 ? wsum[wid - 1] : 0) + carry;
        if (i < N) cnt[i] = pre + x - v;   // exclusive prefix
        int total = wsum[15] + carry;
        __syncthreads();
        if (t == 0) carry = total;
        __syncthreads();
    }
}

// scatter_build: coalesced reads of all per-edge inputs; one scattered 40 B
// record write at the edge's dst-sorted position. Removes ALL gather
// indirection from the fused kernel (except the irreducible y[src] gather).
__global__ __launch_bounds__(256) void scatter_build_kernel(
    const int* __restrict__ edst,
    const int* __restrict__ esrc,
    const void* __restrict__ eattr,  // E x 4
    const void* __restrict__ ele,    // E x 10
    const int* __restrict__ flagp,
    int* __restrict__ cnt,
    unsigned char* __restrict__ rec, int E)
{
    int i = blockIdx.x * 256 + threadIdx.x;
    if (i >= E) return;
    int f = *flagp;
    int d = edst[i];
    int p = atomicAdd(&cnt[d], 1);

    unsigned e0 = f2b(ldin(ele, (size_t)i * NB + 0, f));
    unsigned e1 = f2b(ldin(ele, (size_t)i * NB + 1, f));
    unsigned e2 = f2b(ldin(ele, (size_t)i * NB + 2, f));
    unsigned e3 = f2b(ldin(ele, (size_t)i * NB + 3, f));
    unsigned e4 = f2b(ldin(ele, (size_t)i * NB + 4, f));
    unsigned e5 = f2b(ldin(ele, (size_t)i * NB + 5, f));
    unsigned e6 = f2b(ldin(ele, (size_t)i * NB + 6, f));
    unsigned e7 = f2b(ldin(ele, (size_t)i * NB + 7, f));
    unsigned e8 = f2b(ldin(ele, (size_t)i * NB + 8, f));
    unsigned e9 = f2b(ldin(ele, (size_t)i * NB + 9, f));
    float ea0 = ldin(eattr, (size_t)i * 4 + 0, f);
    float ea1 = ldin(eattr, (size_t)i * 4 + 1, f);
    float ea2 = ldin(eattr, (size_t)i * 4 + 2, f);
    float ea3 = ldin(eattr, (size_t)i * 4 + 3, f);

    unsigned char* r = rec + (size_t)p * REC;
    *(int2*)(r + 0)    = make_int2(esrc[i], (int)(e0 | (e1 << 16)));
    *(int2*)(r + 8)    = make_int2((int)(e2 | (e3 << 16)), (int)(e4 | (e5 << 16)));
    *(int2*)(r + 16)   = make_int2((int)(e6 | (e7 << 16)), (int)(e8 | (e9 << 16)));
    *(float2*)(r + 24) = make_float2(ea0, ea1);
    *(float2*)(r + 32) = make_float2(ea2, ea3);
}

// ---------------------------------------------------------------------------
// node_y: y = fctp(x, attr, W_l10, W_l11) -> bf16 [N,128] PLANAR:
// y[n] = [ y0(32) | y1_d0(u:32) | y1_d1(32) | y1_d2(32) ]
// ---------------------------------------------------------------------------
__global__ __launch_bounds__(256) void node_y_kernel(
    const void* __restrict__ node_input,
    const void* __restrict__ node_attr,
    const void* __restrict__ Wl10,
    const void* __restrict__ Wl11,
    const int* __restrict__ flagp,
    unsigned short* __restrict__ y, int N)
{
    __shared__ float sW0[1024];
    __shared__ float sW1[1024];
    __shared__ float sX[16 * 128];
    int f = *flagp;
    int t = threadIdx.x;
    for (int i = t; i < 1024; i += 256) {
        sW0[i] = ldin(Wl10, i, f);
        sW1[i] = ldin(Wl11, i, f);
    }
    int n0 = blockIdx.x * 16;
    for (int i = t; i < 2048; i += 256) {
        int ln = i >> 7, c = i & 127, n = n0 + ln;
        sX[i] = (n < N) ? ldin(node_input, (size_t)n * F4 + c, f) : 0.f;
    }
    __syncthreads();
    for (int i = t; i < 2048; i += 256) {
        int ln = i >> 7, c = i & 127, n = n0 + ln;
        if (n >= N) continue;
        float attr = ldin(node_attr, n, f);
        float acc = 0.f;
        if (c < 32) {
#pragma unroll
            for (int u = 0; u < 32; u++) acc += sX[ln * 128 + u] * sW0[u * 32 + c];
        } else {
            int d = (c - 32) >> 5, u0 = (c - 32) & 31;
#pragma unroll
            for (int u = 0; u < 32; u++) acc += sX[ln * 128 + 32 + u * 3 + d] * sW1[u * 32 + u0];
        }
        y[(size_t)n * F4 + c] = f2b(acc * attr * INV_SQRT32);
    }
}

// ---------------------------------------------------------------------------
// Owner-computes fused edge kernel: block b owns dst nodes [3b, 3b+3).
// Processes that node range's dst-sorted edges in <=64-edge tiles:
//   P1: h = silu(ele@W1/sqrt10) via MFMA  -> sHW
//   P2: w = h@W2 *0.1 via MFMA            -> sHW (aliased)
//   PC: per-lane A-fragment build; 16 MFMA proj -> sFeat (bf16, overlays sHW)
//   reduce: thread t<128 accumulates channel t of each owned node in regs.
// Final: plain coalesced f32 stores of 3 agg rows. ZERO aggregation atomics.
// ---------------------------------------------------------------------------
#define SM_ELEB  0        // ushort[64*32]   4096
#define SM_HW    4096     // ushort[64*136] 17408
#define SM_EA    21504    // float[64*4]     1024
#define SM_SRC   22528    // int[64]          256
#define SM_TOTAL 22784    // x7 blocks = 159488 <= 163840

__global__ __launch_bounds__(256, 7) void fused_edge_kernel(
    const unsigned char* __restrict__ rec,    // E x 40, dst-sorted records
    const int* __restrict__ cnt,              // N bucket END offsets
    const unsigned short* __restrict__ y,     // N x 128 bf16 planar
    const unsigned short* __restrict__ w1t,   // 112 x 32
    const unsigned short* __restrict__ w2t,   // 128 x 128
    const unsigned short* __restrict__ w20t,  // 32 x 64
    const unsigned short* __restrict__ w21t,  // 32 x 64
    float* __restrict__ agg,                  // N x 128 fp32
    int N)
{
    __shared__ __align__(16) char smem[SM_TOTAL];
    unsigned short* sEleB = (unsigned short*)(smem + SM_ELEB);
    unsigned short* sHW = (unsigned short*)(smem + SM_HW);
    float* sEa = (float*)(smem + SM_EA);
    int* sSrc = (int*)(smem + SM_SRC);

    int t = threadIdx.x;
    int n0 = blockIdx.x * 3;
    int e_begin = (n0 > 0) ? cnt[n0 - 1] : 0;
    int bnd0 = cnt[n0];
    int bnd1 = cnt[(n0 + 1 < N) ? n0 + 1 : N - 1];
    int e_end = cnt[(n0 + 2 < N) ? n0 + 2 : N - 1];
    int M = e_end - e_begin;

    int w = t >> 6, lane = t & 63;
    int lm = lane & 15, quad = lane >> 4;
    int em = w * 16 + lm;

    float ac0 = 0.f, ac1 = 0.f, ac2 = 0.f;   // per-channel accumulators (t<128)

    int ntiles = (M + 63) >> 6;
    for (int tile = 0; tile < ntiles; tile++) {
        int base = e_begin + tile * 64;
        int ne = M - tile * 64;
        if (ne > 64) ne = 64;

        // ---- stage from sorted records (sequential region, ~2.5KB) ----
        if (t < 64)
            sSrc[t] = (t < ne) ? *(const int*)(rec + (size_t)(base + t) * REC) : 0;
        for (int i = t; i < 64 * 32; i += 256) {
            int e = i >> 5, k = i & 31;
            unsigned short v = 0;
            if (k < NB && e < ne)
                v = *(const unsigned short*)(rec + (size_t)(base + e) * REC + 4 + 2 * k);
            sEleB[i] = v;
        }
        {
            int e = t >> 2;
            sEa[t] = (e < ne) ? *(const float*)(rec + (size_t)(base + e) * REC + 24 + 4 * (t & 3)) : 0.f;
        }
        __syncthreads();

        // ---- y row gather: the one irreducible random access ----
        const unsigned short* yrg = y + (size_t)sSrc[em] * 128;
        short8 x0  = *(const short8*)(yrg + quad * 8);
        short8 xd0 = *(const short8*)(yrg + 32 + quad * 8);
        short8 xd1 = *(const short8*)(yrg + 64 + quad * 8);
        short8 xd2 = *(const short8*)(yrg + 96 + quad * 8);

        // ---- P1: GEMM1 + silu -> sHW ----
        {
            short8 a = *(const short8*)(sEleB + (w * 16 + lm) * 32 + quad * 8);
            float4v c1[7];
#pragma unroll
            for (int nt = 0; nt < 7; nt++) {
                c1[nt] = (float4v){0.f, 0.f, 0.f, 0.f};
                short8 b = *(const short8*)(w1t + (nt * 16 + lm) * 32 + quad * 8);
                c1[nt] = __builtin_amdgcn_mfma_f32_16x16x32_bf16(a, b, c1[nt], 0, 0, 0);
            }
#pragma unroll
            for (int nt = 0; nt < 7; nt++) {
                int ch = nt * 16 + lm;
#pragma unroll
                for (int r = 0; r < 4; r++) {
                    int row = w * 16 + quad * 4 + r;
                    float hv = 0.f;
                    if (ch < NH) {
                        float aa = c1[nt][r] * INV_SQRT10;
                        hv = aa / (1.f + __expf(-aa));
                    }
                    sHW[row * EROW + ch] = f2b(hv);
                }
            }
            // zero k in [112,128)
            int e = t >> 2, seg = t & 3;
            *(uint2*)(sHW + e * EROW + 112 + seg * 4) = (uint2){0u, 0u};
        }
        __syncthreads();

        // ---- P2: GEMM2 (read h frags, barrier, overwrite with wout) ----
        short8 hfr[4];
#pragma unroll
        for (int kc = 0; kc < 4; kc++)
            hfr[kc] = *(const short8*)(sHW + (w * 16 + lm) * EROW + kc * 32 + quad * 8);
        __syncthreads();
        {
            float4v c2[8];
#pragma unroll
            for (int nt = 0; nt < 8; nt++) c2[nt] = (float4v){0.f, 0.f, 0.f, 0.f};
#pragma unroll
            for (int kc = 0; kc < 4; kc++) {
#pragma unroll
                for (int nt = 0; nt < 8; nt++) {
                    short8 b = *(const short8*)(w2t + (nt * 16 + lm) * 128 + kc * 32 + quad * 8);
                    c2[nt] = __builtin_amdgcn_mfma_f32_16x16x32_bf16(hfr[kc], b, c2[nt], 0, 0, 0);
                }
            }
#pragma unroll
            for (int nt = 0; nt < 8; nt++)
#pragma unroll
                for (int r = 0; r < 4; r++)
                    sHW[(w * 16 + quad * 4 + r) * EROW + nt * 16 + lm] = f2b(c2[nt][r] * INV_SQRT100);
        }
        __syncthreads();

        // ---- PC: build A-frags in regs, project via MFMA ----
        {
            const unsigned short* wr = sHW + em * EROW;
            short8 wA = *(const short8*)(wr + quad * 8);
            short8 wB = *(const short8*)(wr + 32 + quad * 8);
            short8 wC = *(const short8*)(wr + 64 + quad * 8);
            short8 wD = *(const short8*)(wr + 96 + quad * 8);
            float ea0 = sEa[em * 4 + 0];
            float e1x = sEa[em * 4 + 1];
            float e1y = sEa[em * 4 + 2];
            float e1z = sEa[em * 4 + 3];
            float ea0S = ea0 * AGG_SCALE;
            float s3 = AGG_SCALE * INV_SQRT3;

            short8 f00, f01, f10, f11, f20, f21, f30, f31;
#pragma unroll
            for (int j = 0; j < 8; j++) {
                float x0f = b2f((unsigned short)x0[j]);
                float d0f = b2f((unsigned short)xd0[j]);
                float d1f = b2f((unsigned short)xd1[j]);
                float d2f = b2f((unsigned short)xd2[j]);
                f00[j] = (short)f2b(b2f((unsigned short)wA[j]) * x0f * ea0S);
                float tt = d0f * e1x + d1f * e1y + d2f * e1z;
                f01[j] = (short)f2b(b2f((unsigned short)wD[j]) * tt * s3);
                float p = b2f((unsigned short)wB[j]) * x0f * AGG_SCALE;
                f10[j] = (short)f2b(p * e1x);
                f20[j] = (short)f2b(p * e1y);
                f30[j] = (short)f2b(p * e1z);
                float q = b2f((unsigned short)wC[j]) * ea0S;
                f11[j] = (short)f2b(q * d0f);
                f21[j] = (short)f2b(q * d1f);
                f31[j] = (short)f2b(q * d2f);
            }

            float4v acc[8];
#pragma unroll
            for (int i = 0; i < 8; i++) acc[i] = (float4v){0.f, 0.f, 0.f, 0.f};
#pragma unroll
            for (int g = 0; g < 4; g++) {
                const unsigned short* wt = g ? w21t : w20t;
                short8 ak0 = (g == 0) ? f00 : (g == 1) ? f10 : (g == 2) ? f20 : f30;
                short8 ak1 = (g == 0) ? f01 : (g == 1) ? f11 : (g == 2) ? f21 : f31;
#pragma unroll
                for (int nt = 0; nt < 2; nt++) {
                    short8 b0 = *(const short8*)(wt + (nt * 16 + lm) * 64 + quad * 8);
                    short8 b1 = *(const short8*)(wt + (nt * 16 + lm) * 64 + 32 + quad * 8);
                    acc[g * 2 + nt] = __builtin_amdgcn_mfma_f32_16x16x32_bf16(ak0, b0, acc[g * 2 + nt], 0, 0, 0);
                    acc[g * 2 + nt] = __builtin_amdgcn_mfma_f32_16x16x32_bf16(ak1, b1, acc[g * 2 + nt], 0, 0, 0);
                }
            }

            // ---- stage features bf16 into LDS (overlay sEleB+sHW, now dead) ----
            __syncthreads();   // all sHW reads above complete
            unsigned short* sFeat = (unsigned short*)smem;   // [64][EROW]
#pragma unroll
            for (int g = 0; g < 4; g++)
#pragma unroll
                for (int nt = 0; nt < 2; nt++) {
                    int ch = (g == 0) ? (nt * 16 + lm) : (32 + (g - 1) * 32 + nt * 16 + lm);
#pragma unroll
                    for (int r = 0; r < 4; r++) {
                        int er = w * 16 + quad * 4 + r;
                        sFeat[er * EROW + ch] = f2b(acc[g * 2 + nt][r]);
                    }
                }
            __syncthreads();

            // ---- reduce into per-node register accumulators ----
            if (t < 128) {
                for (int e = 0; e < ne; e++) {
                    float v = b2f(sFeat[e * EROW + t]);
                    int ge = base + e;
                    if (ge < bnd0)      ac0 += v;
                    else if (ge < bnd1) ac1 += v;
                    else                ac2 += v;
                }
            }
            __syncthreads();   // protect sFeat/sEleB before next tile's staging
        }
    }

    // ---- plain coalesced stores of owned agg rows (no atomics, no memset) ----
    if (t < 128) {
        agg[(size_t)n0 * F4 + t] = ac0;
        if (n0 + 1 < N) agg[(size_t)(n0 + 1) * F4 + t] = ac1;
        if (n0 + 2 < N) agg[(size_t)(n0 + 2) * F4 + t] = ac2;
    }
}

// ---------------------------------------------------------------------------
// out: out = attr*(c_s * sc(x) + c_x * agg * INV8); 16 nodes/block
// agg layout: c<32 -> z0[c]; z1[u][d] at 32 + d*32 + u
// ---------------------------------------------------------------------------
__global__ __launch_bounds__(256) void out_kernel(
    const void* __restrict__ node_input,
    const void* __restrict__ node_attr,
    const void* __restrict__ Wsc0,
    const void* __restrict__ Wsc1,
    const float* __restrict__ agg,   // N x 128
    const int* __restrict__ flagp,
    void* __restrict__ out, int N)
{
    __shared__ float sWs0[1024], sWs1[1024];
    __shared__ float sX[16 * 128];
    __shared__ float sA[16 * 128];
    int f = *flagp;
    int t = threadIdx.x;
    for (int i = t; i < 1024; i += 256) {
        sWs0[i] = ldin(Wsc0, i, f);
        sWs1[i] = ldin(Wsc1, i, f);
    }
    int n0 = blockIdx.x * 16;
    for (int i = t; i < 2048; i += 256) {
        int ln = i >> 7, c = i & 127, n = n0 + ln;
        sX[i] = (n < N) ? ldin(node_input, (size_t)n * F4 + c, f) : 0.f;
        sA[i] = (n < N) ? agg[(size_t)n * F4 + c] : 0.f;
    }
    __syncthreads();
    for (int i = t; i < 2048; i += 256) {
        int ln = i >> 7, c = i & 127, n = n0 + ln;
        if (n >= N) continue;
        float attr = ldin(node_attr, n, f);
        float s, z;
        if (c < 32) {
            float as = 0.f;
#pragma unroll
            for (int u = 0; u < 32; u++) as += sX[ln * 128 + u] * sWs0[u * 32 + c];
            s = as * INV_SQRT32;
            z = sA[ln * 128 + c];
        } else {
            int i2 = c - 32;
            int u0 = i2 / 3, d = i2 - u0 * 3;
            float as = 0.f;
#pragma unroll
            for (int u = 0; u < 32; u++) as += sX[ln * 128 + 32 + u * 3 + d] * sWs1[u * 32 + u0];
            s = as * INV_SQRT32;
            z = sA[ln * 128 + 32 + d * 32 + u0];
        }
        float val = attr * (C_S * s + C_X * z * INV8);
        size_t oi = (size_t)n * F4 + c;
        if (f) ((float*)out)[oi] = val;
        else   ((__hip_bfloat16*)out)[oi] = __float2bfloat16(val);
    }
}

// ---------------------------------------------------------------------------
extern "C" void kernel_launch(void* const* d_in, const int* in_sizes, int n_in,
                              void* d_out, int out_size, void* d_ws, size_t ws_size,
                              hipStream_t stream) {
    const void* node_input = d_in[0];
    const void* node_attr  = d_in[1];
    const int* edge_src    = (const int*)d_in[2];
    const int* edge_dst    = (const int*)d_in[3];
    const void* edge_attr  = d_in[4];
    const void* ele        = d_in[5];
    const void* Wsc0       = d_in[6];
    const void* Wsc1       = d_in[7];
    const void* Wl10       = d_in[8];
    const void* Wl11       = d_in[9];
    const void* Wl20       = d_in[10];
    const void* Wl21       = d_in[11];
    const void* Wfc1       = d_in[12];
    const void* Wfc2       = d_in[13];

    int N = in_sizes[0] / F4;   // 50000
    int E = in_sizes[2];        // 800000

    char* ws = (char*)d_ws;
    int* flag = (int*)ws;                                        // 64 B
    unsigned short* y = (unsigned short*)(ws + 64);              // N*128 bf16
    size_t y_b = (size_t)N * F4 * 2;
    float* agg = (float*)(ws + 64 + y_b);                        // N*128 fp32
    size_t agg_b = (size_t)N * F4 * 4;
    size_t off = 64 + y_b + agg_b;
    unsigned short* w2t  = (unsigned short*)(ws + off);          // 32 KB
    unsigned short* w20t = (unsigned short*)(ws + off + 32768);  // 4 KB
    unsigned short* w21t = (unsigned short*)(ws + off + 36864);  // 4 KB
    unsigned short* w1t  = (unsigned short*)(ws + off + 40960);  // 7 KB
    size_t off2 = off + 49152;
    int* cnt = (int*)(ws + off2);                                // N ints
    size_t cnt_b = ((size_t)N * 4 + 63) & ~(size_t)63;
    unsigned char* rec = (unsigned char*)(ws + off2 + cnt_b);    // E*40 B

    detect_dtype_kernel<<<1, 1, 0, stream>>>(node_attr, flag);
    prep_kernel<<<1, 256, 0, stream>>>(Wfc1, Wfc2, Wl20, Wl21, flag, w1t, w2t, w20t, w21t);
    (void)hipMemsetAsync(cnt, 0, (size_t)N * 4, stream);

    // counting sort of edges by dst, materializing sorted 40 B records
    hist_kernel<<<(E + 255) / 256, 256, 0, stream>>>(edge_dst, cnt, E);
    scan_kernel<<<1, 1024, 0, stream>>>(cnt, N);
    scatter_build_kernel<<<(E + 255) / 256, 256, 0, stream>>>(
        edge_dst, edge_src, edge_attr, ele, flag, cnt, rec, E);

    node_y_kernel<<<(N + 15) / 16, 256, 0, stream>>>(node_input, node_attr, Wl10, Wl11, flag, y, N);

    fused_edge_kernel<<<(N + 2) / 3, 256, 0, stream>>>(
        rec, cnt, y, w1t, w2t, w20t, w21t, agg, N);

    out_kernel<<<(N + 15) / 16, 256, 0, stream>>>(node_input, node_attr, Wsc0, Wsc1,
                                                  agg, flag, d_out, N);
}

// Round 5
// 1178.601 us; speedup vs baseline: 1.7457x; 1.7457x over previous
//
#include <hip/hip_runtime.h>
#include <hip/hip_bf16.h>

#define MUL 32
#define F4 128
#define NB 10
#define NH 100
#define EROW 136   // LDS row stride (ushorts) for sHW/sFeat: 272 B = 17*16, 16B-aligned rows
#define REC 40     // bytes per sorted edge record: src int @0, ele bf16[10] @4, ea f32[4] @24

#define INV_SQRT32 0.17677669529663687f
#define INV_SQRT10 0.31622776601683794f
#define INV_SQRT100 0.1f
#define INV_SQRT3 0.5773502691896258f
#define AGG_SCALE 0.25f   // 1/sqrt(16)
#define INV8 0.125f       // 1/sqrt(64)
#define C_S 0.3826834323650898f
#define C_X 0.9238795325112867f

typedef __attribute__((ext_vector_type(8))) short short8;
typedef __attribute__((ext_vector_type(4))) float float4v;

__device__ __forceinline__ float bf2f(__hip_bfloat16 v) { return __bfloat162float(v); }
__device__ __forceinline__ unsigned short f2b(float x) {
    __hip_bfloat16 b = __float2bfloat16(x);
    return *(unsigned short*)&b;
}
__device__ __forceinline__ float b2f(unsigned short u) {
    __hip_bfloat16 b;
    *(unsigned short*)&b = u;
    return __bfloat162float(b);
}
// flag: 1 = inputs fp32, 0 = inputs bf16
__device__ __forceinline__ float ldin(const void* p, size_t i, int f) {
    return f ? ((const float*)p)[i] : bf2f(((const __hip_bfloat16*)p)[i]);
}

// ---------------------------------------------------------------------------
__global__ void detect_dtype_kernel(const void* __restrict__ node_attr, int* __restrict__ flag) {
    unsigned w = *(const unsigned*)node_attr;
    *flag = (w == 0x3F800000u) ? 1 : 0;
}

// ---------------------------------------------------------------------------
// prep: k-contiguous bf16 B-operands.
// ---------------------------------------------------------------------------
__global__ __launch_bounds__(256) void prep_kernel(
    const void* __restrict__ Wfc1,   // 10 x 100
    const void* __restrict__ Wfc2,   // 100 x 128
    const void* __restrict__ Wl20,   // 64 x 32
    const void* __restrict__ Wl21,   // 64 x 32
    const int* __restrict__ flagp,
    unsigned short* __restrict__ w1t,
    unsigned short* __restrict__ w2t,
    unsigned short* __restrict__ w20t,
    unsigned short* __restrict__ w21t)
{
    int f = *flagp;
    int t = threadIdx.x;
    for (int i = t; i < 128 * 128; i += 256) {
        int n = i >> 7, k = i & 127;
        w2t[i] = (k < NH) ? f2b(ldin(Wfc2, (size_t)k * 128 + n, f)) : 0;
    }
    for (int i = t; i < 32 * 64; i += 256) {
        int v = i >> 6, u = i & 63;
        w20t[i] = f2b(ldin(Wl20, (size_t)u * 32 + v, f));
        w21t[i] = f2b(ldin(Wl21, (size_t)u * 32 + v, f));
    }
    for (int i = t; i < 112 * 32; i += 256) {
        int n = i >> 5, k = i & 31;
        w1t[i] = (k < NB && n < NH) ? f2b(ldin(Wfc1, (size_t)k * NH + n, f)) : 0;
    }
}

// ---------------------------------------------------------------------------
// Counting sort of edges by dst: hist -> 3-phase scan -> scatter_build.
// After scatter_build, cnt[n] = END offset of bucket n (== start of bucket n+1).
// ---------------------------------------------------------------------------
__global__ __launch_bounds__(256) void hist_kernel(
    const int* __restrict__ edst, int* __restrict__ cnt, int E)
{
    int i = blockIdx.x * 256 + threadIdx.x;
    if (i < E) atomicAdd(&cnt[edst[i]], 1);
}

// phase A: per-block exclusive scan of 1024-elem chunk; block total -> bsum
__global__ __launch_bounds__(1024) void scanA_kernel(
    int* __restrict__ cnt, int* __restrict__ bsum, int N)
{
    __shared__ int wsum[16];
    int t = threadIdx.x, lane = t & 63, wid = t >> 6;
    int i = blockIdx.x * 1024 + t;
    int v = (i < N) ? cnt[i] : 0;
    int x = v;
#pragma unroll
    for (int d = 1; d < 64; d <<= 1) { int yv = __shfl_up(x, d); if (lane >= d) x += yv; }
    if (lane == 63) wsum[wid] = x;
    __syncthreads();
    if (wid == 0 && lane < 16) {
        int s = wsum[lane];
#pragma unroll
        for (int d = 1; d < 16; d <<= 1) { int yv = __shfl_up(s, d); if (lane >= d) s += yv; }
        wsum[lane] = s;
    }
    __syncthreads();
    int pre = (wid > 0 ? wsum[wid - 1] : 0);
    if (i < N) cnt[i] = pre + x - v;          // exclusive within chunk
    if (t == 0) bsum[blockIdx.x] = wsum[15];  // chunk total
}

// phase B: single-wave exclusive scan of block totals (nb <= a few hundred)
__global__ __launch_bounds__(64) void scanB_kernel(int* __restrict__ bsum, int nb)
{
    int t = threadIdx.x;
    int carry = 0;
    for (int c0 = 0; c0 < nb; c0 += 64) {
        int idx = c0 + t;
        int v = (idx < nb) ? bsum[idx] : 0;
        int x = v;
#pragma unroll
        for (int d = 1; d < 64; d <<= 1) { int yv = __shfl_up(x, d); if (t >= d) x += yv; }
        if (idx < nb) bsum[idx] = carry + x - v;
        carry += __shfl(x, 63);
    }
}

// phase C: add chunk offsets
__global__ __launch_bounds__(1024) void scanC_kernel(
    int* __restrict__ cnt, const int* __restrict__ bsum, int N)
{
    int i = blockIdx.x * 1024 + threadIdx.x;
    if (i < N) cnt[i] += bsum[blockIdx.x];
}

// scatter_build: coalesced reads of all per-edge inputs; one scattered 40 B
// record write at the edge's dst-sorted position. Removes ALL gather
// indirection from the fused kernel (except the irreducible y[src] gather).
__global__ __launch_bounds__(256) void scatter_build_kernel(
    const int* __restrict__ edst,
    const int* __restrict__ esrc,
    const void* __restrict__ eattr,  // E x 4
    const void* __restrict__ ele,    // E x 10
    const int* __restrict__ flagp,
    int* __restrict__ cnt,
    unsigned char* __restrict__ rec, int E)
{
    int i = blockIdx.x * 256 + threadIdx.x;
    if (i >= E) return;
    int f = *flagp;
    int d = edst[i];
    int p = atomicAdd(&cnt[d], 1);

    unsigned e0 = f2b(ldin(ele, (size_t)i * NB + 0, f));
    unsigned e1 = f2b(ldin(ele, (size_t)i * NB + 1, f));
    unsigned e2 = f2b(ldin(ele, (size_t)i * NB + 2, f));
    unsigned e3 = f2b(ldin(ele, (size_t)i * NB + 3, f));
    unsigned e4 = f2b(ldin(ele, (size_t)i * NB + 4, f));
    unsigned e5 = f2b(ldin(ele, (size_t)i * NB + 5, f));
    unsigned e6 = f2b(ldin(ele, (size_t)i * NB + 6, f));
    unsigned e7 = f2b(ldin(ele, (size_t)i * NB + 7, f));
    unsigned e8 = f2b(ldin(ele, (size_t)i * NB + 8, f));
    unsigned e9 = f2b(ldin(ele, (size_t)i * NB + 9, f));
    float ea0 = ldin(eattr, (size_t)i * 4 + 0, f);
    float ea1 = ldin(eattr, (size_t)i * 4 + 1, f);
    float ea2 = ldin(eattr, (size_t)i * 4 + 2, f);
    float ea3 = ldin(eattr, (size_t)i * 4 + 3, f);

    unsigned char* r = rec + (size_t)p * REC;
    *(int2*)(r + 0)    = make_int2(esrc[i], (int)(e0 | (e1 << 16)));
    *(int2*)(r + 8)    = make_int2((int)(e2 | (e3 << 16)), (int)(e4 | (e5 << 16)));
    *(int2*)(r + 16)   = make_int2((int)(e6 | (e7 << 16)), (int)(e8 | (e9 << 16)));
    *(float2*)(r + 24) = make_float2(ea0, ea1);
    *(float2*)(r + 32) = make_float2(ea2, ea3);
}

// ---------------------------------------------------------------------------
// node_y: y = fctp(x, attr, W_l10, W_l11) -> bf16 [N,128] PLANAR:
// y[n] = [ y0(32) | y1_d0(u:32) | y1_d1(32) | y1_d2(32) ]
// ---------------------------------------------------------------------------
__global__ __launch_bounds__(256) void node_y_kernel(
    const void* __restrict__ node_input,
    const void* __restrict__ node_attr,
    const void* __restrict__ Wl10,
    const void* __restrict__ Wl11,
    const int* __restrict__ flagp,
    unsigned short* __restrict__ y, int N)
{
    __shared__ float sW0[1024];
    __shared__ float sW1[1024];
    __shared__ float sX[16 * 128];
    int f = *flagp;
    int t = threadIdx.x;
    for (int i = t; i < 1024; i += 256) {
        sW0[i] = ldin(Wl10, i, f);
        sW1[i] = ldin(Wl11, i, f);
    }
    int n0 = blockIdx.x * 16;
    for (int i = t; i < 2048; i += 256) {
        int ln = i >> 7, c = i & 127, n = n0 + ln;
        sX[i] = (n < N) ? ldin(node_input, (size_t)n * F4 + c, f) : 0.f;
    }
    __syncthreads();
    for (int i = t; i < 2048; i += 256) {
        int ln = i >> 7, c = i & 127, n = n0 + ln;
        if (n >= N) continue;
        float attr = ldin(node_attr, n, f);
        float acc = 0.f;
        if (c < 32) {
#pragma unroll
            for (int u = 0; u < 32; u++) acc += sX[ln * 128 + u] * sW0[u * 32 + c];
        } else {
            int d = (c - 32) >> 5, u0 = (c - 32) & 31;
#pragma unroll
            for (int u = 0; u < 32; u++) acc += sX[ln * 128 + 32 + u * 3 + d] * sW1[u * 32 + u0];
        }
        y[(size_t)n * F4 + c] = f2b(acc * attr * INV_SQRT32);
    }
}

// ---------------------------------------------------------------------------
// Owner-computes fused edge kernel: block b owns dst nodes [3b, 3b+3).
// Processes that node range's dst-sorted edges in <=64-edge tiles:
//   P1: h = silu(ele@W1/sqrt10) via MFMA  -> sHW
//   P2: w = h@W2 *0.1 via MFMA            -> sHW (aliased)
//   PC: per-lane A-fragment build; 16 MFMA proj -> sFeat (bf16, overlays sHW)
//   reduce: thread t<128 accumulates channel t of each owned node in regs.
// Final: plain coalesced f32 stores of 3 agg rows. ZERO aggregation atomics.
// __launch_bounds__(256,4): VGPR cap 128 — (256,7) capped at 73 and spilled
// the fragment arrays to scratch (round-4: 5.7 GB HBM spill traffic).
// ---------------------------------------------------------------------------
#define SM_ELEB  0        // ushort[64*32]   4096
#define SM_HW    4096     // ushort[64*136] 17408
#define SM_EA    21504    // float[64*4]     1024
#define SM_SRC   22528    // int[64]          256
#define SM_TOTAL 22784

__global__ __launch_bounds__(256, 4) void fused_edge_kernel(
    const unsigned char* __restrict__ rec,    // E x 40, dst-sorted records
    const int* __restrict__ cnt,              // N bucket END offsets
    const unsigned short* __restrict__ y,     // N x 128 bf16 planar
    const unsigned short* __restrict__ w1t,   // 112 x 32
    const unsigned short* __restrict__ w2t,   // 128 x 128
    const unsigned short* __restrict__ w20t,  // 32 x 64
    const unsigned short* __restrict__ w21t,  // 32 x 64
    float* __restrict__ agg,                  // N x 128 fp32
    int N)
{
    __shared__ __align__(16) char smem[SM_TOTAL];
    unsigned short* sEleB = (unsigned short*)(smem + SM_ELEB);
    unsigned short* sHW = (unsigned short*)(smem + SM_HW);
    float* sEa = (float*)(smem + SM_EA);
    int* sSrc = (int*)(smem + SM_SRC);

    int t = threadIdx.x;
    int n0 = blockIdx.x * 3;
    int e_begin = (n0 > 0) ? cnt[n0 - 1] : 0;
    int bnd0 = cnt[n0];
    int bnd1 = cnt[(n0 + 1 < N) ? n0 + 1 : N - 1];
    int e_end = cnt[(n0 + 2 < N) ? n0 + 2 : N - 1];
    int M = e_end - e_begin;

    int w = t >> 6, lane = t & 63;
    int lm = lane & 15, quad = lane >> 4;
    int em = w * 16 + lm;

    float ac0 = 0.f, ac1 = 0.f, ac2 = 0.f;   // per-channel accumulators (t<128)

    int ntiles = (M + 63) >> 6;
    for (int tile = 0; tile < ntiles; tile++) {
        int base = e_begin + tile * 64;
        int ne = M - tile * 64;
        if (ne > 64) ne = 64;

        // ---- stage from sorted records (sequential region, ~2.5KB) ----
        if (t < 64)
            sSrc[t] = (t < ne) ? *(const int*)(rec + (size_t)(base + t) * REC) : 0;
        for (int i = t; i < 64 * 32; i += 256) {
            int e = i >> 5, k = i & 31;
            unsigned short v = 0;
            if (k < NB && e < ne)
                v = *(const unsigned short*)(rec + (size_t)(base + e) * REC + 4 + 2 * k);
            sEleB[i] = v;
        }
        {
            int e = t >> 2;
            sEa[t] = (e < ne) ? *(const float*)(rec + (size_t)(base + e) * REC + 24 + 4 * (t & 3)) : 0.f;
        }
        __syncthreads();

        // ---- y row gather: the one irreducible random access ----
        const unsigned short* yrg = y + (size_t)sSrc[em] * 128;
        short8 x0  = *(const short8*)(yrg + quad * 8);
        short8 xd0 = *(const short8*)(yrg + 32 + quad * 8);
        short8 xd1 = *(const short8*)(yrg + 64 + quad * 8);
        short8 xd2 = *(const short8*)(yrg + 96 + quad * 8);

        // ---- P1: GEMM1 + silu -> sHW ----
        {
            short8 a = *(const short8*)(sEleB + (w * 16 + lm) * 32 + quad * 8);
            float4v c1[7];
#pragma unroll
            for (int nt = 0; nt < 7; nt++) {
                c1[nt] = (float4v){0.f, 0.f, 0.f, 0.f};
                short8 b = *(const short8*)(w1t + (nt * 16 + lm) * 32 + quad * 8);
                c1[nt] = __builtin_amdgcn_mfma_f32_16x16x32_bf16(a, b, c1[nt], 0, 0, 0);
            }
#pragma unroll
            for (int nt = 0; nt < 7; nt++) {
                int ch = nt * 16 + lm;
#pragma unroll
                for (int r = 0; r < 4; r++) {
                    int row = w * 16 + quad * 4 + r;
                    float hv = 0.f;
                    if (ch < NH) {
                        float aa = c1[nt][r] * INV_SQRT10;
                        hv = aa / (1.f + __expf(-aa));
                    }
                    sHW[row * EROW + ch] = f2b(hv);
                }
            }
            // zero k in [112,128)
            int e = t >> 2, seg = t & 3;
            *(uint2*)(sHW + e * EROW + 112 + seg * 4) = (uint2){0u, 0u};
        }
        __syncthreads();

        // ---- P2: GEMM2 (read h frags, barrier, overwrite with wout) ----
        short8 hfr[4];
#pragma unroll
        for (int kc = 0; kc < 4; kc++)
            hfr[kc] = *(const short8*)(sHW + (w * 16 + lm) * EROW + kc * 32 + quad * 8);
        __syncthreads();
        {
            float4v c2[8];
#pragma unroll
            for (int nt = 0; nt < 8; nt++) c2[nt] = (float4v){0.f, 0.f, 0.f, 0.f};
#pragma unroll
            for (int kc = 0; kc < 4; kc++) {
#pragma unroll
                for (int nt = 0; nt < 8; nt++) {
                    short8 b = *(const short8*)(w2t + (nt * 16 + lm) * 128 + kc * 32 + quad * 8);
                    c2[nt] = __builtin_amdgcn_mfma_f32_16x16x32_bf16(hfr[kc], b, c2[nt], 0, 0, 0);
                }
            }
#pragma unroll
            for (int nt = 0; nt < 8; nt++)
#pragma unroll
                for (int r = 0; r < 4; r++)
                    sHW[(w * 16 + quad * 4 + r) * EROW + nt * 16 + lm] = f2b(c2[nt][r] * INV_SQRT100);
        }
        __syncthreads();

        // ---- PC: build A-frags in regs, project via MFMA ----
        {
            const unsigned short* wr = sHW + em * EROW;
            short8 wA = *(const short8*)(wr + quad * 8);
            short8 wB = *(const short8*)(wr + 32 + quad * 8);
            short8 wC = *(const short8*)(wr + 64 + quad * 8);
            short8 wD = *(const short8*)(wr + 96 + quad * 8);
            float ea0 = sEa[em * 4 + 0];
            float e1x = sEa[em * 4 + 1];
            float e1y = sEa[em * 4 + 2];
            float e1z = sEa[em * 4 + 3];
            float ea0S = ea0 * AGG_SCALE;
            float s3 = AGG_SCALE * INV_SQRT3;

            short8 f00, f01, f10, f11, f20, f21, f30, f31;
#pragma unroll
            for (int j = 0; j < 8; j++) {
                float x0f = b2f((unsigned short)x0[j]);
                float d0f = b2f((unsigned short)xd0[j]);
                float d1f = b2f((unsigned short)xd1[j]);
                float d2f = b2f((unsigned short)xd2[j]);
                f00[j] = (short)f2b(b2f((unsigned short)wA[j]) * x0f * ea0S);
                float tt = d0f * e1x + d1f * e1y + d2f * e1z;
                f01[j] = (short)f2b(b2f((unsigned short)wD[j]) * tt * s3);
                float p = b2f((unsigned short)wB[j]) * x0f * AGG_SCALE;
                f10[j] = (short)f2b(p * e1x);
                f20[j] = (short)f2b(p * e1y);
                f30[j] = (short)f2b(p * e1z);
                float q = b2f((unsigned short)wC[j]) * ea0S;
                f11[j] = (short)f2b(q * d0f);
                f21[j] = (short)f2b(q * d1f);
                f31[j] = (short)f2b(q * d2f);
            }

            float4v acc[8];
#pragma unroll
            for (int i = 0; i < 8; i++) acc[i] = (float4v){0.f, 0.f, 0.f, 0.f};
#pragma unroll
            for (int g = 0; g < 4; g++) {
                const unsigned short* wt = g ? w21t : w20t;
                short8 ak0 = (g == 0) ? f00 : (g == 1) ? f10 : (g == 2) ? f20 : f30;
                short8 ak1 = (g == 0) ? f01 : (g == 1) ? f11 : (g == 2) ? f21 : f31;
#pragma unroll
                for (int nt = 0; nt < 2; nt++) {
                    short8 b0 = *(const short8*)(wt + (nt * 16 + lm) * 64 + quad * 8);
                    short8 b1 = *(const short8*)(wt + (nt * 16 + lm) * 64 + 32 + quad * 8);
                    acc[g * 2 + nt] = __builtin_amdgcn_mfma_f32_16x16x32_bf16(ak0, b0, acc[g * 2 + nt], 0, 0, 0);
                    acc[g * 2 + nt] = __builtin_amdgcn_mfma_f32_16x16x32_bf16(ak1, b1, acc[g * 2 + nt], 0, 0, 0);
                }
            }

            // ---- stage features bf16 into LDS (overlay sEleB+sHW, now dead) ----
            __syncthreads();   // all sHW reads above complete
            unsigned short* sFeat = (unsigned short*)smem;   // [64][EROW]
#pragma unroll
            for (int g = 0; g < 4; g++)
#pragma unroll
                for (int nt = 0; nt < 2; nt++) {
                    int ch = (g == 0) ? (nt * 16 + lm) : (32 + (g - 1) * 32 + nt * 16 + lm);
#pragma unroll
                    for (int r = 0; r < 4; r++) {
                        int er = w * 16 + quad * 4 + r;
                        sFeat[er * EROW + ch] = f2b(acc[g * 2 + nt][r]);
                    }
                }
            __syncthreads();

            // ---- reduce into per-node register accumulators ----
            if (t < 128) {
                for (int e = 0; e < ne; e++) {
                    float v = b2f(sFeat[e * EROW + t]);
                    int ge = base + e;
                    if (ge < bnd0)      ac0 += v;
                    else if (ge < bnd1) ac1 += v;
                    else                ac2 += v;
                }
            }
            __syncthreads();   // protect sFeat/sEleB before next tile's staging
        }
    }

    // ---- plain coalesced stores of owned agg rows (no atomics, no memset) ----
    if (t < 128) {
        agg[(size_t)n0 * F4 + t] = ac0;
        if (n0 + 1 < N) agg[(size_t)(n0 + 1) * F4 + t] = ac1;
        if (n0 + 2 < N) agg[(size_t)(n0 + 2) * F4 + t] = ac2;
    }
}

// ---------------------------------------------------------------------------
// out: out = attr*(c_s * sc(x) + c_x * agg * INV8); 16 nodes/block
// agg layout: c<32 -> z0[c]; z1[u][d] at 32 + d*32 + u
// ---------------------------------------------------------------------------
__global__ __launch_bounds__(256) void out_kernel(
    const void* __restrict__ node_input,
    const void* __restrict__ node_attr,
    const void* __restrict__ Wsc0,
    const void* __restrict__ Wsc1,
    const float* __restrict__ agg,   // N x 128
    const int* __restrict__ flagp,
    void* __restrict__ out, int N)
{
    __shared__ float sWs0[1024], sWs1[1024];
    __shared__ float sX[16 * 128];
    __shared__ float sA[16 * 128];
    int f = *flagp;
    int t = threadIdx.x;
    for (int i = t; i < 1024; i += 256) {
        sWs0[i] = ldin(Wsc0, i, f);
        sWs1[i] = ldin(Wsc1, i, f);
    }
    int n0 = blockIdx.x * 16;
    for (int i = t; i < 2048; i += 256) {
        int ln = i >> 7, c = i & 127, n = n0 + ln;
        sX[i] = (n < N) ? ldin(node_input, (size_t)n * F4 + c, f) : 0.f;
        sA[i] = (n < N) ? agg[(size_t)n * F4 + c] : 0.f;
    }
    __syncthreads();
    for (int i = t; i < 2048; i += 256) {
        int ln = i >> 7, c = i & 127, n = n0 + ln;
        if (n >= N) continue;
        float attr = ldin(node_attr, n, f);
        float s, z;
        if (c < 32) {
            float as = 0.f;
#pragma unroll
            for (int u = 0; u < 32; u++) as += sX[ln * 128 + u] * sWs0[u * 32 + c];
            s = as * INV_SQRT32;
            z = sA[ln * 128 + c];
        } else {
            int i2 = c - 32;
            int u0 = i2 / 3, d = i2 - u0 * 3;
            float as = 0.f;
#pragma unroll
            for (int u = 0; u < 32; u++) as += sX[ln * 128 + 32 + u * 3 + d] * sWs1[u * 32 + u0];
            s = as * INV_SQRT32;
            z = sA[ln * 128 + 32 + d * 32 + u0];
        }
        float val = attr * (C_S * s + C_X * z * INV8);
        size_t oi = (size_t)n * F4 + c;
        if (f) ((float*)out)[oi] = val;
        else   ((__hip_bfloat16*)out)[oi] = __float2bfloat16(val);
    }
}

// ---------------------------------------------------------------------------
extern "C" void kernel_launch(void* const* d_in, const int* in_sizes, int n_in,
                              void* d_out, int out_size, void* d_ws, size_t ws_size,
                              hipStream_t stream) {
    const void* node_input = d_in[0];
    const void* node_attr  = d_in[1];
    const int* edge_src    = (const int*)d_in[2];
    const int* edge_dst    = (const int*)d_in[3];
    const void* edge_attr  = d_in[4];
    const void* ele        = d_in[5];
    const void* Wsc0       = d_in[6];
    const void* Wsc1       = d_in[7];
    const void* Wl10       = d_in[8];
    const void* Wl11       = d_in[9];
    const void* Wl20       = d_in[10];
    const void* Wl21       = d_in[11];
    const void* Wfc1       = d_in[12];
    const void* Wfc2       = d_in[13];

    int N = in_sizes[0] / F4;   // 50000
    int E = in_sizes[2];        // 800000

    char* ws = (char*)d_ws;
    int* flag = (int*)ws;                                        // 64 B
    unsigned short* y = (unsigned short*)(ws + 64);              // N*128 bf16
    size_t y_b = (size_t)N * F4 * 2;
    float* agg = (float*)(ws + 64 + y_b);                        // N*128 fp32
    size_t agg_b = (size_t)N * F4 * 4;
    size_t off = 64 + y_b + agg_b;
    unsigned short* w2t  = (unsigned short*)(ws + off);          // 32 KB
    unsigned short* w20t = (unsigned short*)(ws + off + 32768);  // 4 KB
    unsigned short* w21t = (unsigned short*)(ws + off + 36864);  // 4 KB
    unsigned short* w1t  = (unsigned short*)(ws + off + 40960);  // 7 KB
    size_t off2 = off + 49152;
    int* cnt = (int*)(ws + off2);                                // N ints
    size_t cnt_b = ((size_t)N * 4 + 63) & ~(size_t)63;
    int* bsum = (int*)(ws + off2 + cnt_b);                       // scan block sums
    size_t bsum_b = 4096;
    unsigned char* rec = (unsigned char*)(ws + off2 + cnt_b + bsum_b);  // E*40 B

    int nscan = (N + 1023) / 1024;

    detect_dtype_kernel<<<1, 1, 0, stream>>>(node_attr, flag);
    prep_kernel<<<1, 256, 0, stream>>>(Wfc1, Wfc2, Wl20, Wl21, flag, w1t, w2t, w20t, w21t);
    (void)hipMemsetAsync(cnt, 0, (size_t)N * 4, stream);

    // counting sort of edges by dst, materializing sorted 40 B records
    hist_kernel<<<(E + 255) / 256, 256, 0, stream>>>(edge_dst, cnt, E);
    scanA_kernel<<<nscan, 1024, 0, stream>>>(cnt, bsum, N);
    scanB_kernel<<<1, 64, 0, stream>>>(bsum, nscan);
    scanC_kernel<<<nscan, 1024, 0, stream>>>(cnt, bsum, N);
    scatter_build_kernel<<<(E + 255) / 256, 256, 0, stream>>>(
        edge_dst, edge_src, edge_attr, ele, flag, cnt, rec, E);

    node_y_kernel<<<(N + 15) / 16, 256, 0, stream>>>(node_input, node_attr, Wl10, Wl11, flag, y, N);

    fused_edge_kernel<<<(N + 2) / 3, 256, 0, stream>>>(
        rec, cnt, y, w1t, w2t, w20t, w21t, agg, N);

    out_kernel<<<(N + 15) / 16, 256, 0, stream>>>(node_input, node_attr, Wsc0, Wsc1,
                                                  agg, flag, d_out, N);
}

// Round 6
// 1170.577 us; speedup vs baseline: 1.7576x; 1.0069x over previous
//
#include <hip/hip_runtime.h>
#include <hip/hip_bf16.h>

#define MUL 32
#define F4 128
#define NB 10
#define NH 100
#define EROW 136   // LDS row stride (ushorts) for sHW/sFeat: 272 B = 17*16, 16B-aligned rows
#define REC 40     // bytes per sorted edge record: src int @0, ele bf16[10] @4, ea f32[4] @24

#define INV_SQRT32 0.17677669529663687f
#define INV_SQRT10 0.31622776601683794f
#define INV_SQRT100 0.1f
#define INV_SQRT3 0.5773502691896258f
#define AGG_SCALE 0.25f   // 1/sqrt(16)
#define INV8 0.125f       // 1/sqrt(64)
#define C_S 0.3826834323650898f
#define C_X 0.9238795325112867f

typedef __attribute__((ext_vector_type(8))) short short8;
typedef __attribute__((ext_vector_type(4))) float float4v;

__device__ __forceinline__ float bf2f(__hip_bfloat16 v) { return __bfloat162float(v); }
__device__ __forceinline__ unsigned short f2b(float x) {
    __hip_bfloat16 b = __float2bfloat16(x);
    return *(unsigned short*)&b;
}
__device__ __forceinline__ float b2f(unsigned short u) {
    __hip_bfloat16 b;
    *(unsigned short*)&b = u;
    return __bfloat162float(b);
}
// flag: 1 = inputs fp32, 0 = inputs bf16
__device__ __forceinline__ float ldin(const void* p, size_t i, int f) {
    return f ? ((const float*)p)[i] : bf2f(((const __hip_bfloat16*)p)[i]);
}

// ---------------------------------------------------------------------------
__global__ void detect_dtype_kernel(const void* __restrict__ node_attr, int* __restrict__ flag) {
    unsigned w = *(const unsigned*)node_attr;
    *flag = (w == 0x3F800000u) ? 1 : 0;
}

// ---------------------------------------------------------------------------
// prep: k-contiguous bf16 B-operands.
// ---------------------------------------------------------------------------
__global__ __launch_bounds__(256) void prep_kernel(
    const void* __restrict__ Wfc1,   // 10 x 100
    const void* __restrict__ Wfc2,   // 100 x 128
    const void* __restrict__ Wl20,   // 64 x 32
    const void* __restrict__ Wl21,   // 64 x 32
    const int* __restrict__ flagp,
    unsigned short* __restrict__ w1t,
    unsigned short* __restrict__ w2t,
    unsigned short* __restrict__ w20t,
    unsigned short* __restrict__ w21t)
{
    int f = *flagp;
    int t = threadIdx.x;
    for (int i = t; i < 128 * 128; i += 256) {
        int n = i >> 7, k = i & 127;
        w2t[i] = (k < NH) ? f2b(ldin(Wfc2, (size_t)k * 128 + n, f)) : 0;
    }
    for (int i = t; i < 32 * 64; i += 256) {
        int v = i >> 6, u = i & 63;
        w20t[i] = f2b(ldin(Wl20, (size_t)u * 32 + v, f));
        w21t[i] = f2b(ldin(Wl21, (size_t)u * 32 + v, f));
    }
    for (int i = t; i < 112 * 32; i += 256) {
        int n = i >> 5, k = i & 31;
        w1t[i] = (k < NB && n < NH) ? f2b(ldin(Wfc1, (size_t)k * NH + n, f)) : 0;
    }
}

// ---------------------------------------------------------------------------
// Counting sort of edges by dst: hist -> 3-phase scan -> scatter_build.
// After scatter_build, cnt[n] = END offset of bucket n (== start of bucket n+1).
// ---------------------------------------------------------------------------
__global__ __launch_bounds__(256) void hist_kernel(
    const int* __restrict__ edst, int* __restrict__ cnt, int E)
{
    int i = blockIdx.x * 256 + threadIdx.x;
    if (i < E) atomicAdd(&cnt[edst[i]], 1);
}

// phase A: per-block exclusive scan of 1024-elem chunk; block total -> bsum
__global__ __launch_bounds__(1024) void scanA_kernel(
    int* __restrict__ cnt, int* __restrict__ bsum, int N)
{
    __shared__ int wsum[16];
    int t = threadIdx.x, lane = t & 63, wid = t >> 6;
    int i = blockIdx.x * 1024 + t;
    int v = (i < N) ? cnt[i] : 0;
    int x = v;
#pragma unroll
    for (int d = 1; d < 64; d <<= 1) { int yv = __shfl_up(x, d); if (lane >= d) x += yv; }
    if (lane == 63) wsum[wid] = x;
    __syncthreads();
    if (wid == 0 && lane < 16) {
        int s = wsum[lane];
#pragma unroll
        for (int d = 1; d < 16; d <<= 1) { int yv = __shfl_up(s, d); if (lane >= d) s += yv; }
        wsum[lane] = s;
    }
    __syncthreads();
    int pre = (wid > 0 ? wsum[wid - 1] : 0);
    if (i < N) cnt[i] = pre + x - v;          // exclusive within chunk
    if (t == 0) bsum[blockIdx.x] = wsum[15];  // chunk total
}

// phase B: single-wave exclusive scan of block totals
__global__ __launch_bounds__(64) void scanB_kernel(int* __restrict__ bsum, int nb)
{
    int t = threadIdx.x;
    int carry = 0;
    for (int c0 = 0; c0 < nb; c0 += 64) {
        int idx = c0 + t;
        int v = (idx < nb) ? bsum[idx] : 0;
        int x = v;
#pragma unroll
        for (int d = 1; d < 64; d <<= 1) { int yv = __shfl_up(x, d); if (t >= d) x += yv; }
        if (idx < nb) bsum[idx] = carry + x - v;
        carry += __shfl(x, 63);
    }
}

// phase C: add chunk offsets
__global__ __launch_bounds__(1024) void scanC_kernel(
    int* __restrict__ cnt, const int* __restrict__ bsum, int N)
{
    int i = blockIdx.x * 1024 + threadIdx.x;
    if (i < N) cnt[i] += bsum[blockIdx.x];
}

// scatter_build: coalesced reads of all per-edge inputs; one scattered 40 B
// record write at the edge's dst-sorted position.
__global__ __launch_bounds__(256) void scatter_build_kernel(
    const int* __restrict__ edst,
    const int* __restrict__ esrc,
    const void* __restrict__ eattr,  // E x 4
    const void* __restrict__ ele,    // E x 10
    const int* __restrict__ flagp,
    int* __restrict__ cnt,
    unsigned char* __restrict__ rec, int E)
{
    int i = blockIdx.x * 256 + threadIdx.x;
    if (i >= E) return;
    int f = *flagp;
    int d = edst[i];
    int p = atomicAdd(&cnt[d], 1);

    unsigned e0 = f2b(ldin(ele, (size_t)i * NB + 0, f));
    unsigned e1 = f2b(ldin(ele, (size_t)i * NB + 1, f));
    unsigned e2 = f2b(ldin(ele, (size_t)i * NB + 2, f));
    unsigned e3 = f2b(ldin(ele, (size_t)i * NB + 3, f));
    unsigned e4 = f2b(ldin(ele, (size_t)i * NB + 4, f));
    unsigned e5 = f2b(ldin(ele, (size_t)i * NB + 5, f));
    unsigned e6 = f2b(ldin(ele, (size_t)i * NB + 6, f));
    unsigned e7 = f2b(ldin(ele, (size_t)i * NB + 7, f));
    unsigned e8 = f2b(ldin(ele, (size_t)i * NB + 8, f));
    unsigned e9 = f2b(ldin(ele, (size_t)i * NB + 9, f));
    float ea0 = ldin(eattr, (size_t)i * 4 + 0, f);
    float ea1 = ldin(eattr, (size_t)i * 4 + 1, f);
    float ea2 = ldin(eattr, (size_t)i * 4 + 2, f);
    float ea3 = ldin(eattr, (size_t)i * 4 + 3, f);

    unsigned char* r = rec + (size_t)p * REC;
    *(int2*)(r + 0)    = make_int2(esrc[i], (int)(e0 | (e1 << 16)));
    *(int2*)(r + 8)    = make_int2((int)(e2 | (e3 << 16)), (int)(e4 | (e5 << 16)));
    *(int2*)(r + 16)   = make_int2((int)(e6 | (e7 << 16)), (int)(e8 | (e9 << 16)));
    *(float2*)(r + 24) = make_float2(ea0, ea1);
    *(float2*)(r + 32) = make_float2(ea2, ea3);
}

// ---------------------------------------------------------------------------
// node_y: y = fctp(x, attr, W_l10, W_l11) -> bf16 [N,128] PLANAR:
// y[n] = [ y0(32) | y1_d0(u:32) | y1_d1(32) | y1_d2(32) ]
// ---------------------------------------------------------------------------
__global__ __launch_bounds__(256) void node_y_kernel(
    const void* __restrict__ node_input,
    const void* __restrict__ node_attr,
    const void* __restrict__ Wl10,
    const void* __restrict__ Wl11,
    const int* __restrict__ flagp,
    unsigned short* __restrict__ y, int N)
{
    __shared__ float sW0[1024];
    __shared__ float sW1[1024];
    __shared__ float sX[16 * 128];
    int f = *flagp;
    int t = threadIdx.x;
    for (int i = t; i < 1024; i += 256) {
        sW0[i] = ldin(Wl10, i, f);
        sW1[i] = ldin(Wl11, i, f);
    }
    int n0 = blockIdx.x * 16;
    for (int i = t; i < 2048; i += 256) {
        int ln = i >> 7, c = i & 127, n = n0 + ln;
        sX[i] = (n < N) ? ldin(node_input, (size_t)n * F4 + c, f) : 0.f;
    }
    __syncthreads();
    for (int i = t; i < 2048; i += 256) {
        int ln = i >> 7, c = i & 127, n = n0 + ln;
        if (n >= N) continue;
        float attr = ldin(node_attr, n, f);
        float acc = 0.f;
        if (c < 32) {
#pragma unroll
            for (int u = 0; u < 32; u++) acc += sX[ln * 128 + u] * sW0[u * 32 + c];
        } else {
            int d = (c - 32) >> 5, u0 = (c - 32) & 31;
#pragma unroll
            for (int u = 0; u < 32; u++) acc += sX[ln * 128 + 32 + u * 3 + d] * sW1[u * 32 + u0];
        }
        y[(size_t)n * F4 + c] = f2b(acc * attr * INV_SQRT32);
    }
}

// ---------------------------------------------------------------------------
// Owner-computes fused edge kernel: block b owns dst nodes [3b, 3b+3).
// Register-pressure discipline (round-5 lesson: gfx950 unified VGPR/AGPR file;
// (256,4) caps arch+acc at 128 combined): every MFMA phase keeps exactly ONE
// accumulator live — compute per output tile, write, move on.
// ---------------------------------------------------------------------------
#define SM_ELEB  0        // ushort[64*32]   4096
#define SM_HW    4096     // ushort[64*136] 17408
#define SM_EA    21504    // float[64*4]     1024
#define SM_SRC   22528    // int[64]          256
#define SM_TOTAL 22784

__global__ __launch_bounds__(256, 4) void fused_edge_kernel(
    const unsigned char* __restrict__ rec,    // E x 40, dst-sorted records
    const int* __restrict__ cnt,              // N bucket END offsets
    const unsigned short* __restrict__ y,     // N x 128 bf16 planar
    const unsigned short* __restrict__ w1t,   // 112 x 32
    const unsigned short* __restrict__ w2t,   // 128 x 128
    const unsigned short* __restrict__ w20t,  // 32 x 64
    const unsigned short* __restrict__ w21t,  // 32 x 64
    float* __restrict__ agg,                  // N x 128 fp32
    int N)
{
    __shared__ __align__(16) char smem[SM_TOTAL];
    unsigned short* sEleB = (unsigned short*)(smem + SM_ELEB);
    unsigned short* sHW = (unsigned short*)(smem + SM_HW);
    float* sEa = (float*)(smem + SM_EA);
    int* sSrc = (int*)(smem + SM_SRC);

    int t = threadIdx.x;
    int n0 = blockIdx.x * 3;
    int e_begin = (n0 > 0) ? cnt[n0 - 1] : 0;
    int bnd0 = cnt[n0];
    int bnd1 = cnt[(n0 + 1 < N) ? n0 + 1 : N - 1];
    int e_end = cnt[(n0 + 2 < N) ? n0 + 2 : N - 1];
    int M = e_end - e_begin;

    int w = t >> 6, lane = t & 63;
    int lm = lane & 15, quad = lane >> 4;
    int em = w * 16 + lm;

    float ac0 = 0.f, ac1 = 0.f, ac2 = 0.f;   // per-channel accumulators (t<128)

    int ntiles = (M + 63) >> 6;
    for (int tile = 0; tile < ntiles; tile++) {
        int base = e_begin + tile * 64;
        int ne = M - tile * 64;
        if (ne > 64) ne = 64;

        // ---- stage from sorted records (sequential region, ~2.5KB) ----
        if (t < 64)
            sSrc[t] = (t < ne) ? *(const int*)(rec + (size_t)(base + t) * REC) : 0;
        for (int i = t; i < 64 * 32; i += 256) {
            int e = i >> 5, k = i & 31;
            unsigned short v = 0;
            if (k < NB && e < ne)
                v = *(const unsigned short*)(rec + (size_t)(base + e) * REC + 4 + 2 * k);
            sEleB[i] = v;
        }
        {
            int e = t >> 2;
            sEa[t] = (e < ne) ? *(const float*)(rec + (size_t)(base + e) * REC + 24 + 4 * (t & 3)) : 0.f;
        }
        __syncthreads();

        // ---- y row gather: the one irreducible random access ----
        const unsigned short* yrg = y + (size_t)sSrc[em] * 128;
        short8 x0  = *(const short8*)(yrg + quad * 8);
        short8 xd0 = *(const short8*)(yrg + 32 + quad * 8);
        short8 xd1 = *(const short8*)(yrg + 64 + quad * 8);
        short8 xd2 = *(const short8*)(yrg + 96 + quad * 8);

        // ---- P1: GEMM1 + silu -> sHW (single live accumulator) ----
        {
            short8 a = *(const short8*)(sEleB + (w * 16 + lm) * 32 + quad * 8);
#pragma unroll
            for (int nt = 0; nt < 7; nt++) {
                float4v c1 = (float4v){0.f, 0.f, 0.f, 0.f};
                short8 b = *(const short8*)(w1t + (nt * 16 + lm) * 32 + quad * 8);
                c1 = __builtin_amdgcn_mfma_f32_16x16x32_bf16(a, b, c1, 0, 0, 0);
                int ch = nt * 16 + lm;
#pragma unroll
                for (int r = 0; r < 4; r++) {
                    int row = w * 16 + quad * 4 + r;
                    float hv = 0.f;
                    if (ch < NH) {
                        float aa = c1[r] * INV_SQRT10;
                        hv = aa / (1.f + __expf(-aa));
                    }
                    sHW[row * EROW + ch] = f2b(hv);
                }
            }
            // zero k in [112,128)
            int e = t >> 2, seg = t & 3;
            *(uint2*)(sHW + e * EROW + 112 + seg * 4) = (uint2){0u, 0u};
        }
        __syncthreads();

        // ---- P2: GEMM2 (read h frags, barrier, overwrite with wout) ----
        short8 hfr[4];
#pragma unroll
        for (int kc = 0; kc < 4; kc++)
            hfr[kc] = *(const short8*)(sHW + (w * 16 + lm) * EROW + kc * 32 + quad * 8);
        __syncthreads();
#pragma unroll
        for (int nt = 0; nt < 8; nt++) {
            float4v c2 = (float4v){0.f, 0.f, 0.f, 0.f};
#pragma unroll
            for (int kc = 0; kc < 4; kc++) {
                short8 b = *(const short8*)(w2t + (nt * 16 + lm) * 128 + kc * 32 + quad * 8);
                c2 = __builtin_amdgcn_mfma_f32_16x16x32_bf16(hfr[kc], b, c2, 0, 0, 0);
            }
#pragma unroll
            for (int r = 0; r < 4; r++)
                sHW[(w * 16 + quad * 4 + r) * EROW + nt * 16 + lm] = f2b(c2[r] * INV_SQRT100);
        }
        __syncthreads();

        // ---- PC: build A-frags in regs, project via MFMA -> sFeat directly ----
        {
            const unsigned short* wr = sHW + em * EROW;
            short8 wA = *(const short8*)(wr + quad * 8);
            short8 wB = *(const short8*)(wr + 32 + quad * 8);
            short8 wC = *(const short8*)(wr + 64 + quad * 8);
            short8 wD = *(const short8*)(wr + 96 + quad * 8);
            float ea0 = sEa[em * 4 + 0];
            float e1x = sEa[em * 4 + 1];
            float e1y = sEa[em * 4 + 2];
            float e1z = sEa[em * 4 + 3];
            float ea0S = ea0 * AGG_SCALE;
            float s3 = AGG_SCALE * INV_SQRT3;

            short8 f00, f01, f10, f11, f20, f21, f30, f31;
#pragma unroll
            for (int j = 0; j < 8; j++) {
                float x0f = b2f((unsigned short)x0[j]);
                float d0f = b2f((unsigned short)xd0[j]);
                float d1f = b2f((unsigned short)xd1[j]);
                float d2f = b2f((unsigned short)xd2[j]);
                f00[j] = (short)f2b(b2f((unsigned short)wA[j]) * x0f * ea0S);
                float tt = d0f * e1x + d1f * e1y + d2f * e1z;
                f01[j] = (short)f2b(b2f((unsigned short)wD[j]) * tt * s3);
                float p = b2f((unsigned short)wB[j]) * x0f * AGG_SCALE;
                f10[j] = (short)f2b(p * e1x);
                f20[j] = (short)f2b(p * e1y);
                f30[j] = (short)f2b(p * e1z);
                float q = b2f((unsigned short)wC[j]) * ea0S;
                f11[j] = (short)f2b(q * d0f);
                f21[j] = (short)f2b(q * d1f);
                f31[j] = (short)f2b(q * d2f);
            }

            // all sHW/sEleB reads complete -> overlay becomes writable
            __syncthreads();
            unsigned short* sFeat = (unsigned short*)smem;   // [64][EROW]
#pragma unroll
            for (int g = 0; g < 4; g++) {
                const unsigned short* wt = g ? w21t : w20t;
                short8 ak0 = (g == 0) ? f00 : (g == 1) ? f10 : (g == 2) ? f20 : f30;
                short8 ak1 = (g == 0) ? f01 : (g == 1) ? f11 : (g == 2) ? f21 : f31;
#pragma unroll
                for (int nt = 0; nt < 2; nt++) {
                    float4v acc = (float4v){0.f, 0.f, 0.f, 0.f};
                    short8 b0 = *(const short8*)(wt + (nt * 16 + lm) * 64 + quad * 8);
                    short8 b1 = *(const short8*)(wt + (nt * 16 + lm) * 64 + 32 + quad * 8);
                    acc = __builtin_amdgcn_mfma_f32_16x16x32_bf16(ak0, b0, acc, 0, 0, 0);
                    acc = __builtin_amdgcn_mfma_f32_16x16x32_bf16(ak1, b1, acc, 0, 0, 0);
                    int ch = (g == 0) ? (nt * 16 + lm) : (32 + (g - 1) * 32 + nt * 16 + lm);
#pragma unroll
                    for (int r = 0; r < 4; r++) {
                        int er = w * 16 + quad * 4 + r;
                        sFeat[er * EROW + ch] = f2b(acc[r]);
                    }
                }
            }
            __syncthreads();

            // ---- reduce into per-node register accumulators ----
            if (t < 128) {
                for (int e = 0; e < ne; e++) {
                    float v = b2f(sFeat[e * EROW + t]);
                    int ge = base + e;
                    if (ge < bnd0)      ac0 += v;
                    else if (ge < bnd1) ac1 += v;
                    else                ac2 += v;
                }
            }
            __syncthreads();   // protect sFeat/sEleB before next tile's staging
        }
    }

    // ---- plain coalesced stores of owned agg rows (no atomics, no memset) ----
    if (t < 128) {
        agg[(size_t)n0 * F4 + t] = ac0;
        if (n0 + 1 < N) agg[(size_t)(n0 + 1) * F4 + t] = ac1;
        if (n0 + 2 < N) agg[(size_t)(n0 + 2) * F4 + t] = ac2;
    }
}

// ---------------------------------------------------------------------------
// out: out = attr*(c_s * sc(x) + c_x * agg * INV8); 16 nodes/block
// agg layout: c<32 -> z0[c]; z1[u][d] at 32 + d*32 + u
// ---------------------------------------------------------------------------
__global__ __launch_bounds__(256) void out_kernel(
    const void* __restrict__ node_input,
    const void* __restrict__ node_attr,
    const void* __restrict__ Wsc0,
    const void* __restrict__ Wsc1,
    const float* __restrict__ agg,   // N x 128
    const int* __restrict__ flagp,
    void* __restrict__ out, int N)
{
    __shared__ float sWs0[1024], sWs1[1024];
    __shared__ float sX[16 * 128];
    __shared__ float sA[16 * 128];
    int f = *flagp;
    int t = threadIdx.x;
    for (int i = t; i < 1024; i += 256) {
        sWs0[i] = ldin(Wsc0, i, f);
        sWs1[i] = ldin(Wsc1, i, f);
    }
    int n0 = blockIdx.x * 16;
    for (int i = t; i < 2048; i += 256) {
        int ln = i >> 7, c = i & 127, n = n0 + ln;
        sX[i] = (n < N) ? ldin(node_input, (size_t)n * F4 + c, f) : 0.f;
        sA[i] = (n < N) ? agg[(size_t)n * F4 + c] : 0.f;
    }
    __syncthreads();
    for (int i = t; i < 2048; i += 256) {
        int ln = i >> 7, c = i & 127, n = n0 + ln;
        if (n >= N) continue;
        float attr = ldin(node_attr, n, f);
        float s, z;
        if (c < 32) {
            float as = 0.f;
#pragma unroll
            for (int u = 0; u < 32; u++) as += sX[ln * 128 + u] * sWs0[u * 32 + c];
            s = as * INV_SQRT32;
            z = sA[ln * 128 + c];
        } else {
            int i2 = c - 32;
            int u0 = i2 / 3, d = i2 - u0 * 3;
            float as = 0.f;
#pragma unroll
            for (int u = 0; u < 32; u++) as += sX[ln * 128 + 32 + u * 3 + d] * sWs1[u * 32 + u0];
            s = as * INV_SQRT32;
            z = sA[ln * 128 + 32 + d * 32 + u0];
        }
        float val = attr * (C_S * s + C_X * z * INV8);
        size_t oi = (size_t)n * F4 + c;
        if (f) ((float*)out)[oi] = val;
        else   ((__hip_bfloat16*)out)[oi] = __float2bfloat16(val);
    }
}

// ---------------------------------------------------------------------------
extern "C" void kernel_launch(void* const* d_in, const int* in_sizes, int n_in,
                              void* d_out, int out_size, void* d_ws, size_t ws_size,
                              hipStream_t stream) {
    const void* node_input = d_in[0];
    const void* node_attr  = d_in[1];
    const int* edge_src    = (const int*)d_in[2];
    const int* edge_dst    = (const int*)d_in[3];
    const void* edge_attr  = d_in[4];
    const void* ele        = d_in[5];
    const void* Wsc0       = d_in[6];
    const void* Wsc1       = d_in[7];
    const void* Wl10       = d_in[8];
    const void* Wl11       = d_in[9];
    const void* Wl20       = d_in[10];
    const void* Wl21       = d_in[11];
    const void* Wfc1       = d_in[12];
    const void* Wfc2       = d_in[13];

    int N = in_sizes[0] / F4;   // 50000
    int E = in_sizes[2];        // 800000

    char* ws = (char*)d_ws;
    int* flag = (int*)ws;                                        // 64 B
    unsigned short* y = (unsigned short*)(ws + 64);              // N*128 bf16
    size_t y_b = (size_t)N * F4 * 2;
    float* agg = (float*)(ws + 64 + y_b);                        // N*128 fp32
    size_t agg_b = (size_t)N * F4 * 4;
    size_t off = 64 + y_b + agg_b;
    unsigned short* w2t  = (unsigned short*)(ws + off);          // 32 KB
    unsigned short* w20t = (unsigned short*)(ws + off + 32768);  // 4 KB
    unsigned short* w21t = (unsigned short*)(ws + off + 36864);  // 4 KB
    unsigned short* w1t  = (unsigned short*)(ws + off + 40960);  // 7 KB
    size_t off2 = off + 49152;
    int* cnt = (int*)(ws + off2);                                // N ints
    size_t cnt_b = ((size_t)N * 4 + 63) & ~(size_t)63;
    int* bsum = (int*)(ws + off2 + cnt_b);                       // scan block sums
    size_t bsum_b = 4096;
    unsigned char* rec = (unsigned char*)(ws + off2 + cnt_b + bsum_b);  // E*40 B

    int nscan = (N + 1023) / 1024;

    detect_dtype_kernel<<<1, 1, 0, stream>>>(node_attr, flag);
    prep_kernel<<<1, 256, 0, stream>>>(Wfc1, Wfc2, Wl20, Wl21, flag, w1t, w2t, w20t, w21t);
    (void)hipMemsetAsync(cnt, 0, (size_t)N * 4, stream);

    // counting sort of edges by dst, materializing sorted 40 B records
    hist_kernel<<<(E + 255) / 256, 256, 0, stream>>>(edge_dst, cnt, E);
    scanA_kernel<<<nscan, 1024, 0, stream>>>(cnt, bsum, N);
    scanB_kernel<<<1, 64, 0, stream>>>(bsum, nscan);
    scanC_kernel<<<nscan, 1024, 0, stream>>>(cnt, bsum, N);
    scatter_build_kernel<<<(E + 255) / 256, 256, 0, stream>>>(
        edge_dst, edge_src, edge_attr, ele, flag, cnt, rec, E);

    node_y_kernel<<<(N + 15) / 16, 256, 0, stream>>>(node_input, node_attr, Wl10, Wl11, flag, y, N);

    fused_edge_kernel<<<(N + 2) / 3, 256, 0, stream>>>(
        rec, cnt, y, w1t, w2t, w20t, w21t, agg, N);

    out_kernel<<<(N + 15) / 16, 256, 0, stream>>>(node_input, node_attr, Wsc0, Wsc1,
                                                  agg, flag, d_out, N);
}

// Round 7
// 673.528 us; speedup vs baseline: 3.0547x; 1.7380x over previous
//
#include <hip/hip_runtime.h>
#include <hip/hip_bf16.h>

#define MUL 32
#define F4 128
#define NB 10
#define NH 100
#define EROW 136   // LDS row stride (ushorts) for sHW/sFeat: 272 B = 17*16, 16B-aligned rows
#define REC 48     // bytes/record: src@0, dst@4, ele bf16[10]@8, pad, ea f32[4]@32

#define INV_SQRT32 0.17677669529663687f
#define INV_SQRT10 0.31622776601683794f
#define INV_SQRT100 0.1f
#define INV_SQRT3 0.5773502691896258f
#define AGG_SCALE 0.25f   // 1/sqrt(16)
#define INV8 0.125f       // 1/sqrt(64)
#define C_S 0.3826834323650898f
#define C_X 0.9238795325112867f

typedef __attribute__((ext_vector_type(8))) short short8;
typedef __attribute__((ext_vector_type(4))) float float4v;

__device__ __forceinline__ float bf2f(__hip_bfloat16 v) { return __bfloat162float(v); }
__device__ __forceinline__ unsigned short f2b(float x) {
    __hip_bfloat16 b = __float2bfloat16(x);
    return *(unsigned short*)&b;
}
__device__ __forceinline__ float b2f(unsigned short u) {
    __hip_bfloat16 b;
    *(unsigned short*)&b = u;
    return __bfloat162float(b);
}
// flag: 1 = inputs fp32, 0 = inputs bf16
__device__ __forceinline__ float ldin(const void* p, size_t i, int f) {
    return f ? ((const float*)p)[i] : bf2f(((const __hip_bfloat16*)p)[i]);
}

// ---------------------------------------------------------------------------
__global__ void detect_dtype_kernel(const void* __restrict__ node_attr, int* __restrict__ flag) {
    unsigned w = *(const unsigned*)node_attr;
    *flag = (w == 0x3F800000u) ? 1 : 0;
}

// ---------------------------------------------------------------------------
// prep: k-contiguous bf16 B-operands. Parallel across 64 blocks.
// ---------------------------------------------------------------------------
__global__ __launch_bounds__(256) void prep_kernel(
    const void* __restrict__ Wfc1,   // 10 x 100
    const void* __restrict__ Wfc2,   // 100 x 128
    const void* __restrict__ Wl20,   // 64 x 32
    const void* __restrict__ Wl21,   // 64 x 32
    const int* __restrict__ flagp,
    unsigned short* __restrict__ w1t,
    unsigned short* __restrict__ w2t,
    unsigned short* __restrict__ w20t,
    unsigned short* __restrict__ w21t)
{
    int f = *flagp;
    int gi = blockIdx.x * 256 + threadIdx.x;
    if (gi < 128 * 128) {
        int n = gi >> 7, k = gi & 127;
        w2t[gi] = (k < NH) ? f2b(ldin(Wfc2, (size_t)k * 128 + n, f)) : 0;
    }
    if (gi < 32 * 64) {
        int v = gi >> 6, u = gi & 63;
        w20t[gi] = f2b(ldin(Wl20, (size_t)u * 32 + v, f));
        w21t[gi] = f2b(ldin(Wl21, (size_t)u * 32 + v, f));
    }
    if (gi < 112 * 32) {
        int n = gi >> 5, k = gi & 31;
        w1t[gi] = (k < NB && n < NH) ? f2b(ldin(Wfc1, (size_t)k * NH + n, f)) : 0;
    }
}

// ---------------------------------------------------------------------------
// Counting sort of edges by dst: hist -> 3-phase scan -> scatter_build.
// After scatter_build, cnt[n] = END offset of bucket n.
// ---------------------------------------------------------------------------
__global__ __launch_bounds__(256) void hist_kernel(
    const int* __restrict__ edst, int* __restrict__ cnt, int E)
{
    int i = blockIdx.x * 256 + threadIdx.x;
    if (i < E) atomicAdd(&cnt[edst[i]], 1);
}

// phase A: per-block exclusive scan of 1024-elem chunk; block total -> bsum
__global__ __launch_bounds__(1024) void scanA_kernel(
    int* __restrict__ cnt, int* __restrict__ bsum, int N)
{
    __shared__ int wsum[16];
    int t = threadIdx.x, lane = t & 63, wid = t >> 6;
    int i = blockIdx.x * 1024 + t;
    int v = (i < N) ? cnt[i] : 0;
    int x = v;
#pragma unroll
    for (int d = 1; d < 64; d <<= 1) { int yv = __shfl_up(x, d); if (lane >= d) x += yv; }
    if (lane == 63) wsum[wid] = x;
    __syncthreads();
    if (wid == 0 && lane < 16) {
        int s = wsum[lane];
#pragma unroll
        for (int d = 1; d < 16; d <<= 1) { int yv = __shfl_up(s, d); if (lane >= d) s += yv; }
        wsum[lane] = s;
    }
    __syncthreads();
    int pre = (wid > 0 ? wsum[wid - 1] : 0);
    if (i < N) cnt[i] = pre + x - v;          // exclusive within chunk
    if (t == 0) bsum[blockIdx.x] = wsum[15];  // chunk total
}

// phase B: single-wave exclusive scan of block totals
__global__ __launch_bounds__(64) void scanB_kernel(int* __restrict__ bsum, int nb)
{
    int t = threadIdx.x;
    int carry = 0;
    for (int c0 = 0; c0 < nb; c0 += 64) {
        int idx = c0 + t;
        int v = (idx < nb) ? bsum[idx] : 0;
        int x = v;
#pragma unroll
        for (int d = 1; d < 64; d <<= 1) { int yv = __shfl_up(x, d); if (t >= d) x += yv; }
        if (idx < nb) bsum[idx] = carry + x - v;
        carry += __shfl(x, 63);
    }
}

// phase C: add chunk offsets
__global__ __launch_bounds__(1024) void scanC_kernel(
    int* __restrict__ cnt, const int* __restrict__ bsum, int N)
{
    int i = blockIdx.x * 1024 + threadIdx.x;
    if (i < N) cnt[i] += bsum[blockIdx.x];
}

// scatter_build: coalesced reads of all per-edge inputs; one scattered 48 B
// record write at the edge's dst-sorted position.
__global__ __launch_bounds__(256) void scatter_build_kernel(
    const int* __restrict__ edst,
    const int* __restrict__ esrc,
    const void* __restrict__ eattr,  // E x 4
    const void* __restrict__ ele,    // E x 10
    const int* __restrict__ flagp,
    int* __restrict__ cnt,
    unsigned char* __restrict__ rec, int E)
{
    int i = blockIdx.x * 256 + threadIdx.x;
    if (i >= E) return;
    int f = *flagp;
    int d = edst[i];
    int p = atomicAdd(&cnt[d], 1);

    unsigned e0 = f2b(ldin(ele, (size_t)i * NB + 0, f));
    unsigned e1 = f2b(ldin(ele, (size_t)i * NB + 1, f));
    unsigned e2 = f2b(ldin(ele, (size_t)i * NB + 2, f));
    unsigned e3 = f2b(ldin(ele, (size_t)i * NB + 3, f));
    unsigned e4 = f2b(ldin(ele, (size_t)i * NB + 4, f));
    unsigned e5 = f2b(ldin(ele, (size_t)i * NB + 5, f));
    unsigned e6 = f2b(ldin(ele, (size_t)i * NB + 6, f));
    unsigned e7 = f2b(ldin(ele, (size_t)i * NB + 7, f));
    unsigned e8 = f2b(ldin(ele, (size_t)i * NB + 8, f));
    unsigned e9 = f2b(ldin(ele, (size_t)i * NB + 9, f));
    float ea0 = ldin(eattr, (size_t)i * 4 + 0, f);
    float ea1 = ldin(eattr, (size_t)i * 4 + 1, f);
    float ea2 = ldin(eattr, (size_t)i * 4 + 2, f);
    float ea3 = ldin(eattr, (size_t)i * 4 + 3, f);

    unsigned char* r = rec + (size_t)p * REC;
    *(int4*)(r + 0)  = make_int4(esrc[i], d, (int)(e0 | (e1 << 16)), (int)(e2 | (e3 << 16)));
    *(int4*)(r + 16) = make_int4((int)(e4 | (e5 << 16)), (int)(e6 | (e7 << 16)), (int)(e8 | (e9 << 16)), 0);
    *(float4*)(r + 32) = make_float4(ea0, ea1, ea2, ea3);
}

// ---------------------------------------------------------------------------
// node_y: y = fctp(x, attr, W_l10, W_l11) -> bf16 [N,128] PLANAR:
// y[n] = [ y0(32) | y1_d0(u:32) | y1_d1(32) | y1_d2(32) ]
// ---------------------------------------------------------------------------
__global__ __launch_bounds__(256) void node_y_kernel(
    const void* __restrict__ node_input,
    const void* __restrict__ node_attr,
    const void* __restrict__ Wl10,
    const void* __restrict__ Wl11,
    const int* __restrict__ flagp,
    unsigned short* __restrict__ y, int N)
{
    __shared__ float sW0[1024];
    __shared__ float sW1[1024];
    __shared__ float sX[16 * 128];
    int f = *flagp;
    int t = threadIdx.x;
    for (int i = t; i < 1024; i += 256) {
        sW0[i] = ldin(Wl10, i, f);
        sW1[i] = ldin(Wl11, i, f);
    }
    int n0 = blockIdx.x * 16;
    for (int i = t; i < 2048; i += 256) {
        int ln = i >> 7, c = i & 127, n = n0 + ln;
        sX[i] = (n < N) ? ldin(node_input, (size_t)n * F4 + c, f) : 0.f;
    }
    __syncthreads();
    for (int i = t; i < 2048; i += 256) {
        int ln = i >> 7, c = i & 127, n = n0 + ln;
        if (n >= N) continue;
        float attr = ldin(node_attr, n, f);
        float acc = 0.f;
        if (c < 32) {
#pragma unroll
            for (int u = 0; u < 32; u++) acc += sX[ln * 128 + u] * sW0[u * 32 + c];
        } else {
            int d = (c - 32) >> 5, u0 = (c - 32) & 31;
#pragma unroll
            for (int u = 0; u < 32; u++) acc += sX[ln * 128 + 32 + u * 3 + d] * sW1[u * 32 + u0];
        }
        y[(size_t)n * F4 + c] = f2b(acc * attr * INV_SQRT32);
    }
}

// ---------------------------------------------------------------------------
// Fused edge kernel over dst-sorted records: ONE fixed 64-edge tile per block
// (round-2 no-spill structure: straight-line, no loop-carried MFMA state).
// P1/P2/PC identical to round 2. Reduce: per-run segmented sum; runs whose
// whole bucket [cnt[d-1],cnt[d]) is inside the tile -> PLAIN STORE (exclusive
// owner); only the <=2 tile-edge-crossing runs use atomicAdd (vs memset-0 agg).
// ---------------------------------------------------------------------------
#define SM_ELEB  0        // ushort[64*32]   4096
#define SM_HW    4096     // ushort[64*136] 17408
#define SM_EA    21504    // float[64*4]     1024
#define SM_SRC   22528    // int[64]          256
#define SM_DST   22784    // int[64]          256
#define SM_TOTAL 23040    // x6 blocks = 138240 <= 163840

__global__ __launch_bounds__(256, 6) void fused_edge_kernel(
    const unsigned char* __restrict__ rec,    // E x 48, dst-sorted records
    const int* __restrict__ cnt,              // N bucket END offsets
    const unsigned short* __restrict__ y,     // N x 128 bf16 planar
    const unsigned short* __restrict__ w1t,   // 112 x 32
    const unsigned short* __restrict__ w2t,   // 128 x 128
    const unsigned short* __restrict__ w20t,  // 32 x 64
    const unsigned short* __restrict__ w21t,  // 32 x 64
    float* __restrict__ agg,                  // N x 128 fp32 (memset 0)
    int E)
{
    __shared__ __align__(16) char smem[SM_TOTAL];
    unsigned short* sEleB = (unsigned short*)(smem + SM_ELEB);
    unsigned short* sHW = (unsigned short*)(smem + SM_HW);
    float* sEa = (float*)(smem + SM_EA);
    int* sSrc = (int*)(smem + SM_SRC);
    int* sDst = (int*)(smem + SM_DST);

    int t = threadIdx.x;
    int base = blockIdx.x * 64;
    int ne = E - base;
    if (ne > 64) ne = 64;

    // ---- stage from sorted records (sequential ~3 KB region) ----
    if (t < 64) {
        if (t < ne) {
            int2 sd = *(const int2*)(rec + (size_t)(base + t) * REC);
            sSrc[t] = sd.x;
            sDst[t] = sd.y;
        } else {
            sSrc[t] = 0;
            sDst[t] = -1;
        }
    }
    for (int i = t; i < 64 * 32; i += 256) {
        int e = i >> 5, k = i & 31;
        unsigned short v = 0;
        if (k < NB && e < ne)
            v = *(const unsigned short*)(rec + (size_t)(base + e) * REC + 8 + 2 * k);
        sEleB[i] = v;
    }
    {
        int e = t >> 2;
        sEa[t] = (e < ne) ? *(const float*)(rec + (size_t)(base + e) * REC + 32 + 4 * (t & 3)) : 0.f;
    }
    __syncthreads();

    int w = t >> 6, lane = t & 63;
    int lm = lane & 15, quad = lane >> 4;
    int em = w * 16 + lm;

    // ---- y row gather: the one irreducible random access ----
    const unsigned short* yrg = y + (size_t)sSrc[em] * 128;
    short8 x0  = *(const short8*)(yrg + quad * 8);
    short8 xd0 = *(const short8*)(yrg + 32 + quad * 8);
    short8 xd1 = *(const short8*)(yrg + 64 + quad * 8);
    short8 xd2 = *(const short8*)(yrg + 96 + quad * 8);

    // ---- P1: GEMM1 + silu -> sHW ----
    {
        short8 a = *(const short8*)(sEleB + (w * 16 + lm) * 32 + quad * 8);
        float4v c1[7];
#pragma unroll
        for (int nt = 0; nt < 7; nt++) {
            c1[nt] = (float4v){0.f, 0.f, 0.f, 0.f};
            short8 b = *(const short8*)(w1t + (nt * 16 + lm) * 32 + quad * 8);
            c1[nt] = __builtin_amdgcn_mfma_f32_16x16x32_bf16(a, b, c1[nt], 0, 0, 0);
        }
#pragma unroll
        for (int nt = 0; nt < 7; nt++) {
            int ch = nt * 16 + lm;
#pragma unroll
            for (int r = 0; r < 4; r++) {
                int row = w * 16 + quad * 4 + r;
                float hv = 0.f;
                if (ch < NH) {
                    float aa = c1[nt][r] * INV_SQRT10;
                    hv = aa / (1.f + __expf(-aa));
                }
                sHW[row * EROW + ch] = f2b(hv);
            }
        }
        // zero k in [112,128)
        int e = t >> 2, seg = t & 3;
        *(uint2*)(sHW + e * EROW + 112 + seg * 4) = (uint2){0u, 0u};
    }
    __syncthreads();

    // ---- P2: GEMM2 (read h frags, barrier, overwrite with wout) ----
    short8 hfr[4];
#pragma unroll
    for (int kc = 0; kc < 4; kc++)
        hfr[kc] = *(const short8*)(sHW + (w * 16 + lm) * EROW + kc * 32 + quad * 8);
    __syncthreads();
    {
        float4v c2[8];
#pragma unroll
        for (int nt = 0; nt < 8; nt++) c2[nt] = (float4v){0.f, 0.f, 0.f, 0.f};
#pragma unroll
        for (int kc = 0; kc < 4; kc++) {
#pragma unroll
            for (int nt = 0; nt < 8; nt++) {
                short8 b = *(const short8*)(w2t + (nt * 16 + lm) * 128 + kc * 32 + quad * 8);
                c2[nt] = __builtin_amdgcn_mfma_f32_16x16x32_bf16(hfr[kc], b, c2[nt], 0, 0, 0);
            }
        }
#pragma unroll
        for (int nt = 0; nt < 8; nt++)
#pragma unroll
            for (int r = 0; r < 4; r++)
                sHW[(w * 16 + quad * 4 + r) * EROW + nt * 16 + lm] = f2b(c2[nt][r] * INV_SQRT100);
    }
    __syncthreads();

    // ---- PC: build A-frags in regs, project via MFMA ----
    {
        const unsigned short* wr = sHW + em * EROW;
        short8 wA = *(const short8*)(wr + quad * 8);
        short8 wB = *(const short8*)(wr + 32 + quad * 8);
        short8 wC = *(const short8*)(wr + 64 + quad * 8);
        short8 wD = *(const short8*)(wr + 96 + quad * 8);
        float ea0 = sEa[em * 4 + 0];
        float e1x = sEa[em * 4 + 1];
        float e1y = sEa[em * 4 + 2];
        float e1z = sEa[em * 4 + 3];
        float ea0S = ea0 * AGG_SCALE;
        float s3 = AGG_SCALE * INV_SQRT3;

        short8 f00, f01, f10, f11, f20, f21, f30, f31;
#pragma unroll
        for (int j = 0; j < 8; j++) {
            float x0f = b2f((unsigned short)x0[j]);
            float d0f = b2f((unsigned short)xd0[j]);
            float d1f = b2f((unsigned short)xd1[j]);
            float d2f = b2f((unsigned short)xd2[j]);
            f00[j] = (short)f2b(b2f((unsigned short)wA[j]) * x0f * ea0S);
            float tt = d0f * e1x + d1f * e1y + d2f * e1z;
            f01[j] = (short)f2b(b2f((unsigned short)wD[j]) * tt * s3);
            float p = b2f((unsigned short)wB[j]) * x0f * AGG_SCALE;
            f10[j] = (short)f2b(p * e1x);
            f20[j] = (short)f2b(p * e1y);
            f30[j] = (short)f2b(p * e1z);
            float q = b2f((unsigned short)wC[j]) * ea0S;
            f11[j] = (short)f2b(q * d0f);
            f21[j] = (short)f2b(q * d1f);
            f31[j] = (short)f2b(q * d2f);
        }

        float4v acc[8];
#pragma unroll
        for (int i = 0; i < 8; i++) acc[i] = (float4v){0.f, 0.f, 0.f, 0.f};
#pragma unroll
        for (int g = 0; g < 4; g++) {
            const unsigned short* wt = g ? w21t : w20t;
            short8 ak0 = (g == 0) ? f00 : (g == 1) ? f10 : (g == 2) ? f20 : f30;
            short8 ak1 = (g == 0) ? f01 : (g == 1) ? f11 : (g == 2) ? f21 : f31;
#pragma unroll
            for (int nt = 0; nt < 2; nt++) {
                short8 b0 = *(const short8*)(wt + (nt * 16 + lm) * 64 + quad * 8);
                short8 b1 = *(const short8*)(wt + (nt * 16 + lm) * 64 + 32 + quad * 8);
                acc[g * 2 + nt] = __builtin_amdgcn_mfma_f32_16x16x32_bf16(ak0, b0, acc[g * 2 + nt], 0, 0, 0);
                acc[g * 2 + nt] = __builtin_amdgcn_mfma_f32_16x16x32_bf16(ak1, b1, acc[g * 2 + nt], 0, 0, 0);
            }
        }

        // ---- stage features bf16 into LDS (overlay sEleB+sHW, now dead) ----
        __syncthreads();   // all sHW/sEleB reads above complete
        unsigned short* sFeat = (unsigned short*)smem;   // [64][EROW]
#pragma unroll
        for (int g = 0; g < 4; g++)
#pragma unroll
            for (int nt = 0; nt < 2; nt++) {
                int ch = (g == 0) ? (nt * 16 + lm) : (32 + (g - 1) * 32 + nt * 16 + lm);
#pragma unroll
                for (int r = 0; r < 4; r++) {
                    int er = w * 16 + quad * 4 + r;
                    sFeat[er * EROW + ch] = f2b(acc[g * 2 + nt][r]);
                }
            }
        __syncthreads();

        // ---- segmented run reduction: interior runs -> plain store;
        //      tile-edge-crossing runs -> atomicAdd. One thread per channel. ----
        if (t < 128) {
            int c = t;
            int e = 0;
            while (e < ne) {
                int d = sDst[e];           // uniform across the 128 threads
                int rs = e;
                do { e++; } while (e < ne && sDst[e] == d);
                if (d < 0) continue;
                float s = 0.f;
                for (int q = rs; q < e; q++) s += b2f(sFeat[q * EROW + c]);
                int bs = (d > 0) ? cnt[d - 1] : 0;   // bucket start
                int be = cnt[d];                     // bucket end
                if (bs >= base && be <= base + ne)
                    agg[(size_t)d * F4 + c] = s;     // exclusive owner
                else
                    atomicAdd(&agg[(size_t)d * F4 + c], s);
            }
        }
    }
}

// ---------------------------------------------------------------------------
// out: out = attr*(c_s * sc(x) + c_x * agg * INV8); 16 nodes/block
// agg layout: c<32 -> z0[c]; z1[u][d] at 32 + d*32 + u
// ---------------------------------------------------------------------------
__global__ __launch_bounds__(256) void out_kernel(
    const void* __restrict__ node_input,
    const void* __restrict__ node_attr,
    const void* __restrict__ Wsc0,
    const void* __restrict__ Wsc1,
    const float* __restrict__ agg,   // N x 128
    const int* __restrict__ flagp,
    void* __restrict__ out, int N)
{
    __shared__ float sWs0[1024], sWs1[1024];
    __shared__ float sX[16 * 128];
    __shared__ float sA[16 * 128];
    int f = *flagp;
    int t = threadIdx.x;
    for (int i = t; i < 1024; i += 256) {
        sWs0[i] = ldin(Wsc0, i, f);
        sWs1[i] = ldin(Wsc1, i, f);
    }
    int n0 = blockIdx.x * 16;
    for (int i = t; i < 2048; i += 256) {
        int ln = i >> 7, c = i & 127, n = n0 + ln;
        sX[i] = (n < N) ? ldin(node_input, (size_t)n * F4 + c, f) : 0.f;
        sA[i] = (n < N) ? agg[(size_t)n * F4 + c] : 0.f;
    }
    __syncthreads();
    for (int i = t; i < 2048; i += 256) {
        int ln = i >> 7, c = i & 127, n = n0 + ln;
        if (n >= N) continue;
        float attr = ldin(node_attr, n, f);
        float s, z;
        if (c < 32) {
            float as = 0.f;
#pragma unroll
            for (int u = 0; u < 32; u++) as += sX[ln * 128 + u] * sWs0[u * 32 + c];
            s = as * INV_SQRT32;
            z = sA[ln * 128 + c];
        } else {
            int i2 = c - 32;
            int u0 = i2 / 3, d = i2 - u0 * 3;
            float as = 0.f;
#pragma unroll
            for (int u = 0; u < 32; u++) as += sX[ln * 128 + 32 + u * 3 + d] * sWs1[u * 32 + u0];
            s = as * INV_SQRT32;
            z = sA[ln * 128 + 32 + d * 32 + u0];
        }
        float val = attr * (C_S * s + C_X * z * INV8);
        size_t oi = (size_t)n * F4 + c;
        if (f) ((float*)out)[oi] = val;
        else   ((__hip_bfloat16*)out)[oi] = __float2bfloat16(val);
    }
}

// ---------------------------------------------------------------------------
extern "C" void kernel_launch(void* const* d_in, const int* in_sizes, int n_in,
                              void* d_out, int out_size, void* d_ws, size_t ws_size,
                              hipStream_t stream) {
    const void* node_input = d_in[0];
    const void* node_attr  = d_in[1];
    const int* edge_src    = (const int*)d_in[2];
    const int* edge_dst    = (const int*)d_in[3];
    const void* edge_attr  = d_in[4];
    const void* ele        = d_in[5];
    const void* Wsc0       = d_in[6];
    const void* Wsc1       = d_in[7];
    const void* Wl10       = d_in[8];
    const void* Wl11       = d_in[9];
    const void* Wl20       = d_in[10];
    const void* Wl21       = d_in[11];
    const void* Wfc1       = d_in[12];
    const void* Wfc2       = d_in[13];

    int N = in_sizes[0] / F4;   // 50000
    int E = in_sizes[2];        // 800000

    char* ws = (char*)d_ws;
    int* flag = (int*)ws;                                        // 64 B
    unsigned short* y = (unsigned short*)(ws + 64);              // N*128 bf16
    size_t y_b = (size_t)N * F4 * 2;
    float* agg = (float*)(ws + 64 + y_b);                        // N*128 fp32
    size_t agg_b = (size_t)N * F4 * 4;
    size_t off = 64 + y_b + agg_b;
    unsigned short* w2t  = (unsigned short*)(ws + off);          // 32 KB
    unsigned short* w20t = (unsigned short*)(ws + off + 32768);  // 4 KB
    unsigned short* w21t = (unsigned short*)(ws + off + 36864);  // 4 KB
    unsigned short* w1t  = (unsigned short*)(ws + off + 40960);  // 7 KB
    size_t off2 = off + 49152;
    int* cnt = (int*)(ws + off2);                                // N ints
    size_t cnt_b = ((size_t)N * 4 + 63) & ~(size_t)63;
    int* bsum = (int*)(ws + off2 + cnt_b);                       // scan block sums
    size_t bsum_b = 4096;
    unsigned char* rec = (unsigned char*)(ws + off2 + cnt_b + bsum_b);  // E*48 B

    int nscan = (N + 1023) / 1024;

    detect_dtype_kernel<<<1, 1, 0, stream>>>(node_attr, flag);
    prep_kernel<<<64, 256, 0, stream>>>(Wfc1, Wfc2, Wl20, Wl21, flag, w1t, w2t, w20t, w21t);
    (void)hipMemsetAsync(cnt, 0, (size_t)N * 4, stream);
    (void)hipMemsetAsync(agg, 0, agg_b, stream);

    // counting sort of edges by dst, materializing sorted 48 B records
    hist_kernel<<<(E + 255) / 256, 256, 0, stream>>>(edge_dst, cnt, E);
    scanA_kernel<<<nscan, 1024, 0, stream>>>(cnt, bsum, N);
    scanB_kernel<<<1, 64, 0, stream>>>(bsum, nscan);
    scanC_kernel<<<nscan, 1024, 0, stream>>>(cnt, bsum, N);
    scatter_build_kernel<<<(E + 255) / 256, 256, 0, stream>>>(
        edge_dst, edge_src, edge_attr, ele, flag, cnt, rec, E);

    node_y_kernel<<<(N + 15) / 16, 256, 0, stream>>>(node_input, node_attr, Wl10, Wl11, flag, y, N);

    fused_edge_kernel<<<(E + 63) / 64, 256, 0, stream>>>(
        rec, cnt, y, w1t, w2t, w20t, w21t, agg, E);

    out_kernel<<<(N + 15) / 16, 256, 0, stream>>>(node_input, node_attr, Wsc0, Wsc1,
                                                  agg, flag, d_out, N);
}

// Round 8
// 642.411 us; speedup vs baseline: 3.2027x; 1.0484x over previous
//
#include <hip/hip_runtime.h>
#include <hip/hip_bf16.h>

#define MUL 32
#define F4 128
#define NB 10
#define NH 100
#define EROW 136   // LDS row stride (ushorts) for sHW/sFeat: 272 B = 17*16, 16B-aligned rows
#define REC 48     // bytes/record: src@0, dst@4, ele bf16[10]@8, pad, ea f32[4]@32

#define INV_SQRT32 0.17677669529663687f
#define INV_SQRT10 0.31622776601683794f
#define INV_SQRT100 0.1f
#define INV_SQRT3 0.5773502691896258f
#define AGG_SCALE 0.25f   // 1/sqrt(16)
#define INV8 0.125f       // 1/sqrt(64)
#define C_S 0.3826834323650898f
#define C_X 0.9238795325112867f

typedef __attribute__((ext_vector_type(8))) short short8;
typedef __attribute__((ext_vector_type(4))) float float4v;

__device__ __forceinline__ float bf2f(__hip_bfloat16 v) { return __bfloat162float(v); }
__device__ __forceinline__ unsigned short f2b(float x) {
    __hip_bfloat16 b = __float2bfloat16(x);
    return *(unsigned short*)&b;
}
__device__ __forceinline__ float b2f(unsigned short u) {
    __hip_bfloat16 b;
    *(unsigned short*)&b = u;
    return __bfloat162float(b);
}
// flag: 1 = inputs fp32, 0 = inputs bf16
__device__ __forceinline__ float ldin(const void* p, size_t i, int f) {
    return f ? ((const float*)p)[i] : bf2f(((const __hip_bfloat16*)p)[i]);
}

// ---------------------------------------------------------------------------
__global__ void detect_dtype_kernel(const void* __restrict__ node_attr, int* __restrict__ flag) {
    unsigned w = *(const unsigned*)node_attr;
    *flag = (w == 0x3F800000u) ? 1 : 0;
}

// ---------------------------------------------------------------------------
// prep: k-contiguous bf16 B-operands. Parallel across 64 blocks.
// ---------------------------------------------------------------------------
__global__ __launch_bounds__(256) void prep_kernel(
    const void* __restrict__ Wfc1,   // 10 x 100
    const void* __restrict__ Wfc2,   // 100 x 128
    const void* __restrict__ Wl20,   // 64 x 32
    const void* __restrict__ Wl21,   // 64 x 32
    const int* __restrict__ flagp,
    unsigned short* __restrict__ w1t,
    unsigned short* __restrict__ w2t,
    unsigned short* __restrict__ w20t,
    unsigned short* __restrict__ w21t)
{
    int f = *flagp;
    int gi = blockIdx.x * 256 + threadIdx.x;
    if (gi < 128 * 128) {
        int n = gi >> 7, k = gi & 127;
        w2t[gi] = (k < NH) ? f2b(ldin(Wfc2, (size_t)k * 128 + n, f)) : 0;
    }
    if (gi < 32 * 64) {
        int v = gi >> 6, u = gi & 63;
        w20t[gi] = f2b(ldin(Wl20, (size_t)u * 32 + v, f));
        w21t[gi] = f2b(ldin(Wl21, (size_t)u * 32 + v, f));
    }
    if (gi < 112 * 32) {
        int n = gi >> 5, k = gi & 31;
        w1t[gi] = (k < NB && n < NH) ? f2b(ldin(Wfc1, (size_t)k * NH + n, f)) : 0;
    }
}

// ---------------------------------------------------------------------------
// Counting sort of edges by dst: hist -> 3-phase scan -> scatter_build.
// After scatter_build, cnt[n] = END offset of bucket n.
// ---------------------------------------------------------------------------
__global__ __launch_bounds__(256) void hist_kernel(
    const int* __restrict__ edst, int* __restrict__ cnt, int E)
{
    int i = blockIdx.x * 256 + threadIdx.x;
    if (i < E) atomicAdd(&cnt[edst[i]], 1);
}

// phase A: per-block exclusive scan of 1024-elem chunk; block total -> bsum
__global__ __launch_bounds__(1024) void scanA_kernel(
    int* __restrict__ cnt, int* __restrict__ bsum, int N)
{
    __shared__ int wsum[16];
    int t = threadIdx.x, lane = t & 63, wid = t >> 6;
    int i = blockIdx.x * 1024 + t;
    int v = (i < N) ? cnt[i] : 0;
    int x = v;
#pragma unroll
    for (int d = 1; d < 64; d <<= 1) { int yv = __shfl_up(x, d); if (lane >= d) x += yv; }
    if (lane == 63) wsum[wid] = x;
    __syncthreads();
    if (wid == 0 && lane < 16) {
        int s = wsum[lane];
#pragma unroll
        for (int d = 1; d < 16; d <<= 1) { int yv = __shfl_up(s, d); if (lane >= d) s += yv; }
        wsum[lane] = s;
    }
    __syncthreads();
    int pre = (wid > 0 ? wsum[wid - 1] : 0);
    if (i < N) cnt[i] = pre + x - v;          // exclusive within chunk
    if (t == 0) bsum[blockIdx.x] = wsum[15];  // chunk total
}

// phase B: single-wave exclusive scan of block totals
__global__ __launch_bounds__(64) void scanB_kernel(int* __restrict__ bsum, int nb)
{
    int t = threadIdx.x;
    int carry = 0;
    for (int c0 = 0; c0 < nb; c0 += 64) {
        int idx = c0 + t;
        int v = (idx < nb) ? bsum[idx] : 0;
        int x = v;
#pragma unroll
        for (int d = 1; d < 64; d <<= 1) { int yv = __shfl_up(x, d); if (t >= d) x += yv; }
        if (idx < nb) bsum[idx] = carry + x - v;
        carry += __shfl(x, 63);
    }
}

// phase C: add chunk offsets
__global__ __launch_bounds__(1024) void scanC_kernel(
    int* __restrict__ cnt, const int* __restrict__ bsum, int N)
{
    int i = blockIdx.x * 1024 + threadIdx.x;
    if (i < N) cnt[i] += bsum[blockIdx.x];
}

// scatter_build: coalesced reads of all per-edge inputs; one scattered 48 B
// record write at the edge's dst-sorted position.
__global__ __launch_bounds__(256) void scatter_build_kernel(
    const int* __restrict__ edst,
    const int* __restrict__ esrc,
    const void* __restrict__ eattr,  // E x 4
    const void* __restrict__ ele,    // E x 10
    const int* __restrict__ flagp,
    int* __restrict__ cnt,
    unsigned char* __restrict__ rec, int E)
{
    int i = blockIdx.x * 256 + threadIdx.x;
    if (i >= E) return;
    int f = *flagp;
    int d = edst[i];
    int p = atomicAdd(&cnt[d], 1);

    unsigned e0 = f2b(ldin(ele, (size_t)i * NB + 0, f));
    unsigned e1 = f2b(ldin(ele, (size_t)i * NB + 1, f));
    unsigned e2 = f2b(ldin(ele, (size_t)i * NB + 2, f));
    unsigned e3 = f2b(ldin(ele, (size_t)i * NB + 3, f));
    unsigned e4 = f2b(ldin(ele, (size_t)i * NB + 4, f));
    unsigned e5 = f2b(ldin(ele, (size_t)i * NB + 5, f));
    unsigned e6 = f2b(ldin(ele, (size_t)i * NB + 6, f));
    unsigned e7 = f2b(ldin(ele, (size_t)i * NB + 7, f));
    unsigned e8 = f2b(ldin(ele, (size_t)i * NB + 8, f));
    unsigned e9 = f2b(ldin(ele, (size_t)i * NB + 9, f));
    float ea0 = ldin(eattr, (size_t)i * 4 + 0, f);
    float ea1 = ldin(eattr, (size_t)i * 4 + 1, f);
    float ea2 = ldin(eattr, (size_t)i * 4 + 2, f);
    float ea3 = ldin(eattr, (size_t)i * 4 + 3, f);

    unsigned char* r = rec + (size_t)p * REC;
    *(int4*)(r + 0)  = make_int4(esrc[i], d, (int)(e0 | (e1 << 16)), (int)(e2 | (e3 << 16)));
    *(int4*)(r + 16) = make_int4((int)(e4 | (e5 << 16)), (int)(e6 | (e7 << 16)), (int)(e8 | (e9 << 16)), 0);
    *(float4*)(r + 32) = make_float4(ea0, ea1, ea2, ea3);
}

// ---------------------------------------------------------------------------
// node_y: y = fctp(x, attr, W_l10, W_l11) -> bf16 [N,128] PLANAR:
// y[n] = [ y0(32) | y1_d0(u:32) | y1_d1(32) | y1_d2(32) ]
// ---------------------------------------------------------------------------
__global__ __launch_bounds__(256) void node_y_kernel(
    const void* __restrict__ node_input,
    const void* __restrict__ node_attr,
    const void* __restrict__ Wl10,
    const void* __restrict__ Wl11,
    const int* __restrict__ flagp,
    unsigned short* __restrict__ y, int N)
{
    __shared__ float sW0[1024];
    __shared__ float sW1[1024];
    __shared__ float sX[16 * 128];
    int f = *flagp;
    int t = threadIdx.x;
    for (int i = t; i < 1024; i += 256) {
        sW0[i] = ldin(Wl10, i, f);
        sW1[i] = ldin(Wl11, i, f);
    }
    int n0 = blockIdx.x * 16;
    for (int i = t; i < 2048; i += 256) {
        int ln = i >> 7, c = i & 127, n = n0 + ln;
        sX[i] = (n < N) ? ldin(node_input, (size_t)n * F4 + c, f) : 0.f;
    }
    __syncthreads();
    for (int i = t; i < 2048; i += 256) {
        int ln = i >> 7, c = i & 127, n = n0 + ln;
        if (n >= N) continue;
        float attr = ldin(node_attr, n, f);
        float acc = 0.f;
        if (c < 32) {
#pragma unroll
            for (int u = 0; u < 32; u++) acc += sX[ln * 128 + u] * sW0[u * 32 + c];
        } else {
            int d = (c - 32) >> 5, u0 = (c - 32) & 31;
#pragma unroll
            for (int u = 0; u < 32; u++) acc += sX[ln * 128 + 32 + u * 3 + d] * sW1[u * 32 + u0];
        }
        y[(size_t)n * F4 + c] = f2b(acc * attr * INV_SQRT32);
    }
}

// ---------------------------------------------------------------------------
// Fused edge kernel over dst-sorted records: ONE fixed 64-edge tile per block.
// Register discipline (rounds 4-7 lesson): NO accumulator arrays, nothing fat
// live across a barrier; (256,4) so the cap (128, unified VGPR+AGPR) fits the
// straight-line body (round-0 precedent: 52 VGPR, zero spill at this bound).
// Reduce: interior runs (bucket fully inside tile) -> plain store;
// tile-edge-crossing runs -> atomicAdd onto memset-0 agg.
// ---------------------------------------------------------------------------
#define SM_ELEB  0        // ushort[64*32]   4096
#define SM_HW    4096     // ushort[64*136] 17408
#define SM_EA    21504    // float[64*4]     1024
#define SM_SRC   22528    // int[64]          256
#define SM_DST   22784    // int[64]          256
#define SM_TOTAL 23040

__global__ __launch_bounds__(256, 4) void fused_edge_kernel(
    const unsigned char* __restrict__ rec,    // E x 48, dst-sorted records
    const int* __restrict__ cnt,              // N bucket END offsets
    const unsigned short* __restrict__ y,     // N x 128 bf16 planar
    const unsigned short* __restrict__ w1t,   // 112 x 32
    const unsigned short* __restrict__ w2t,   // 128 x 128
    const unsigned short* __restrict__ w20t,  // 32 x 64
    const unsigned short* __restrict__ w21t,  // 32 x 64
    float* __restrict__ agg,                  // N x 128 fp32 (memset 0)
    int E)
{
    __shared__ __align__(16) char smem[SM_TOTAL];
    unsigned short* sEleB = (unsigned short*)(smem + SM_ELEB);
    unsigned short* sHW = (unsigned short*)(smem + SM_HW);
    float* sEa = (float*)(smem + SM_EA);
    int* sSrc = (int*)(smem + SM_SRC);
    int* sDst = (int*)(smem + SM_DST);

    int t = threadIdx.x;
    int base = blockIdx.x * 64;
    int ne = E - base;
    if (ne > 64) ne = 64;

    // ---- stage from sorted records (sequential ~3 KB region) ----
    if (t < 64) {
        if (t < ne) {
            int2 sd = *(const int2*)(rec + (size_t)(base + t) * REC);
            sSrc[t] = sd.x;
            sDst[t] = sd.y;
        } else {
            sSrc[t] = 0;
            sDst[t] = -1;
        }
    }
    for (int i = t; i < 64 * 32; i += 256) {
        int e = i >> 5, k = i & 31;
        unsigned short v = 0;
        if (k < NB && e < ne)
            v = *(const unsigned short*)(rec + (size_t)(base + e) * REC + 8 + 2 * k);
        sEleB[i] = v;
    }
    {
        int e = t >> 2;
        sEa[t] = (e < ne) ? *(const float*)(rec + (size_t)(base + e) * REC + 32 + 4 * (t & 3)) : 0.f;
    }
    __syncthreads();

    int w = t >> 6, lane = t & 63;
    int lm = lane & 15, quad = lane >> 4;
    int em = w * 16 + lm;

    // ---- y row gather: the one irreducible random access ----
    const unsigned short* yrg = y + (size_t)sSrc[em] * 128;
    short8 x0  = *(const short8*)(yrg + quad * 8);
    short8 xd0 = *(const short8*)(yrg + 32 + quad * 8);
    short8 xd1 = *(const short8*)(yrg + 64 + quad * 8);
    short8 xd2 = *(const short8*)(yrg + 96 + quad * 8);

    // ---- P1: GEMM1 + silu -> sHW (single live accumulator) ----
    {
        short8 a = *(const short8*)(sEleB + (w * 16 + lm) * 32 + quad * 8);
#pragma unroll
        for (int nt = 0; nt < 7; nt++) {
            float4v c1 = (float4v){0.f, 0.f, 0.f, 0.f};
            short8 b = *(const short8*)(w1t + (nt * 16 + lm) * 32 + quad * 8);
            c1 = __builtin_amdgcn_mfma_f32_16x16x32_bf16(a, b, c1, 0, 0, 0);
            int ch = nt * 16 + lm;
#pragma unroll
            for (int r = 0; r < 4; r++) {
                int row = w * 16 + quad * 4 + r;
                float hv = 0.f;
                if (ch < NH) {
                    float aa = c1[r] * INV_SQRT10;
                    hv = aa / (1.f + __expf(-aa));
                }
                sHW[row * EROW + ch] = f2b(hv);
            }
        }
        // zero k in [112,128)
        int e = t >> 2, seg = t & 3;
        *(uint2*)(sHW + e * EROW + 112 + seg * 4) = (uint2){0u, 0u};
    }
    __syncthreads();

    // ---- P2: GEMM2, nt-outer single accumulator ----
    short8 hfr[4];
#pragma unroll
    for (int kc = 0; kc < 4; kc++)
        hfr[kc] = *(const short8*)(sHW + (w * 16 + lm) * EROW + kc * 32 + quad * 8);
    __syncthreads();
#pragma unroll
    for (int nt = 0; nt < 8; nt++) {
        float4v c2 = (float4v){0.f, 0.f, 0.f, 0.f};
#pragma unroll
        for (int kc = 0; kc < 4; kc++) {
            short8 b = *(const short8*)(w2t + (nt * 16 + lm) * 128 + kc * 32 + quad * 8);
            c2 = __builtin_amdgcn_mfma_f32_16x16x32_bf16(hfr[kc], b, c2, 0, 0, 0);
        }
#pragma unroll
        for (int r = 0; r < 4; r++)
            sHW[(w * 16 + quad * 4 + r) * EROW + nt * 16 + lm] = f2b(c2[r] * INV_SQRT100);
    }
    __syncthreads();

    // ---- PC: fragment build, barrier, then MFMA -> sFeat direct ----
    {
        const unsigned short* wr = sHW + em * EROW;
        short8 wA = *(const short8*)(wr + quad * 8);
        short8 wB = *(const short8*)(wr + 32 + quad * 8);
        short8 wC = *(const short8*)(wr + 64 + quad * 8);
        short8 wD = *(const short8*)(wr + 96 + quad * 8);
        float ea0 = sEa[em * 4 + 0];
        float e1x = sEa[em * 4 + 1];
        float e1y = sEa[em * 4 + 2];
        float e1z = sEa[em * 4 + 3];
        float ea0S = ea0 * AGG_SCALE;
        float s3 = AGG_SCALE * INV_SQRT3;

        short8 f00, f01, f10, f11, f20, f21, f30, f31;
#pragma unroll
        for (int j = 0; j < 8; j++) {
            float x0f = b2f((unsigned short)x0[j]);
            float d0f = b2f((unsigned short)xd0[j]);
            float d1f = b2f((unsigned short)xd1[j]);
            float d2f = b2f((unsigned short)xd2[j]);
            f00[j] = (short)f2b(b2f((unsigned short)wA[j]) * x0f * ea0S);
            float tt = d0f * e1x + d1f * e1y + d2f * e1z;
            f01[j] = (short)f2b(b2f((unsigned short)wD[j]) * tt * s3);
            float p = b2f((unsigned short)wB[j]) * x0f * AGG_SCALE;
            f10[j] = (short)f2b(p * e1x);
            f20[j] = (short)f2b(p * e1y);
            f30[j] = (short)f2b(p * e1z);
            float q = b2f((unsigned short)wC[j]) * ea0S;
            f11[j] = (short)f2b(q * d0f);
            f21[j] = (short)f2b(q * d1f);
            f31[j] = (short)f2b(q * d2f);
        }

        // all sHW/sEleB reads complete -> overlay becomes writable.
        // MFMA results stream straight to sFeat: no acc array crosses this barrier.
        __syncthreads();
        unsigned short* sFeat = (unsigned short*)smem;   // [64][EROW]
#pragma unroll
        for (int g = 0; g < 4; g++) {
            const unsigned short* wt = g ? w21t : w20t;
            short8 ak0 = (g == 0) ? f00 : (g == 1) ? f10 : (g == 2) ? f20 : f30;
            short8 ak1 = (g == 0) ? f01 : (g == 1) ? f11 : (g == 2) ? f21 : f31;
#pragma unroll
            for (int nt = 0; nt < 2; nt++) {
                float4v acc = (float4v){0.f, 0.f, 0.f, 0.f};
                short8 b0 = *(const short8*)(wt + (nt * 16 + lm) * 64 + quad * 8);
                short8 b1 = *(const short8*)(wt + (nt * 16 + lm) * 64 + 32 + quad * 8);
                acc = __builtin_amdgcn_mfma_f32_16x16x32_bf16(ak0, b0, acc, 0, 0, 0);
                acc = __builtin_amdgcn_mfma_f32_16x16x32_bf16(ak1, b1, acc, 0, 0, 0);
                int ch = (g == 0) ? (nt * 16 + lm) : (32 + (g - 1) * 32 + nt * 16 + lm);
#pragma unroll
                for (int r = 0; r < 4; r++) {
                    int er = w * 16 + quad * 4 + r;
                    sFeat[er * EROW + ch] = f2b(acc[r]);
                }
            }
        }
        __syncthreads();

        // ---- segmented run reduction: interior runs -> plain store;
        //      tile-edge-crossing runs -> atomicAdd. One thread per channel. ----
        if (t < 128) {
            int c = t;
            int e = 0;
            while (e < ne) {
                int d = sDst[e];           // uniform across the 128 threads
                int rs = e;
                do { e++; } while (e < ne && sDst[e] == d);
                if (d < 0) continue;
                float s = 0.f;
                for (int q = rs; q < e; q++) s += b2f(sFeat[q * EROW + c]);
                int bs = (d > 0) ? cnt[d - 1] : 0;   // bucket start
                int be = cnt[d];                     // bucket end
                if (bs >= base && be <= base + ne)
                    agg[(size_t)d * F4 + c] = s;     // exclusive owner
                else
                    atomicAdd(&agg[(size_t)d * F4 + c], s);
            }
        }
    }
}

// ---------------------------------------------------------------------------
// out: out = attr*(c_s * sc(x) + c_x * agg * INV8); 16 nodes/block
// agg layout: c<32 -> z0[c]; z1[u][d] at 32 + d*32 + u
// ---------------------------------------------------------------------------
__global__ __launch_bounds__(256) void out_kernel(
    const void* __restrict__ node_input,
    const void* __restrict__ node_attr,
    const void* __restrict__ Wsc0,
    const void* __restrict__ Wsc1,
    const float* __restrict__ agg,   // N x 128
    const int* __restrict__ flagp,
    void* __restrict__ out, int N)
{
    __shared__ float sWs0[1024], sWs1[1024];
    __shared__ float sX[16 * 128];
    __shared__ float sA[16 * 128];
    int f = *flagp;
    int t = threadIdx.x;
    for (int i = t; i < 1024; i += 256) {
        sWs0[i] = ldin(Wsc0, i, f);
        sWs1[i] = ldin(Wsc1, i, f);
    }
    int n0 = blockIdx.x * 16;
    for (int i = t; i < 2048; i += 256) {
        int ln = i >> 7, c = i & 127, n = n0 + ln;
        sX[i] = (n < N) ? ldin(node_input, (size_t)n * F4 + c, f) : 0.f;
        sA[i] = (n < N) ? agg[(size_t)n * F4 + c] : 0.f;
    }
    __syncthreads();
    for (int i = t; i < 2048; i += 256) {
        int ln = i >> 7, c = i & 127, n = n0 + ln;
        if (n >= N) continue;
        float attr = ldin(node_attr, n, f);
        float s, z;
        if (c < 32) {
            float as = 0.f;
#pragma unroll
            for (int u = 0; u < 32; u++) as += sX[ln * 128 + u] * sWs0[u * 32 + c];
            s = as * INV_SQRT32;
            z = sA[ln * 128 + c];
        } else {
            int i2 = c - 32;
            int u0 = i2 / 3, d = i2 - u0 * 3;
            float as = 0.f;
#pragma unroll
            for (int u = 0; u < 32; u++) as += sX[ln * 128 + 32 + u * 3 + d] * sWs1[u * 32 + u0];
            s = as * INV_SQRT32;
            z = sA[ln * 128 + 32 + d * 32 + u0];
        }
        float val = attr * (C_S * s + C_X * z * INV8);
        size_t oi = (size_t)n * F4 + c;
        if (f) ((float*)out)[oi] = val;
        else   ((__hip_bfloat16*)out)[oi] = __float2bfloat16(val);
    }
}

// ---------------------------------------------------------------------------
extern "C" void kernel_launch(void* const* d_in, const int* in_sizes, int n_in,
                              void* d_out, int out_size, void* d_ws, size_t ws_size,
                              hipStream_t stream) {
    const void* node_input = d_in[0];
    const void* node_attr  = d_in[1];
    const int* edge_src    = (const int*)d_in[2];
    const int* edge_dst    = (const int*)d_in[3];
    const void* edge_attr  = d_in[4];
    const void* ele        = d_in[5];
    const void* Wsc0       = d_in[6];
    const void* Wsc1       = d_in[7];
    const void* Wl10       = d_in[8];
    const void* Wl11       = d_in[9];
    const void* Wl20       = d_in[10];
    const void* Wl21       = d_in[11];
    const void* Wfc1       = d_in[12];
    const void* Wfc2       = d_in[13];

    int N = in_sizes[0] / F4;   // 50000
    int E = in_sizes[2];        // 800000

    char* ws = (char*)d_ws;
    int* flag = (int*)ws;                                        // 64 B
    unsigned short* y = (unsigned short*)(ws + 64);              // N*128 bf16
    size_t y_b = (size_t)N * F4 * 2;
    float* agg = (float*)(ws + 64 + y_b);                        // N*128 fp32
    size_t agg_b = (size_t)N * F4 * 4;
    size_t off = 64 + y_b + agg_b;
    unsigned short* w2t  = (unsigned short*)(ws + off);          // 32 KB
    unsigned short* w20t = (unsigned short*)(ws + off + 32768);  // 4 KB
    unsigned short* w21t = (unsigned short*)(ws + off + 36864);  // 4 KB
    unsigned short* w1t  = (unsigned short*)(ws + off + 40960);  // 7 KB
    size_t off2 = off + 49152;
    int* cnt = (int*)(ws + off2);                                // N ints
    size_t cnt_b = ((size_t)N * 4 + 63) & ~(size_t)63;
    int* bsum = (int*)(ws + off2 + cnt_b);                       // scan block sums
    size_t bsum_b = 4096;
    unsigned char* rec = (unsigned char*)(ws + off2 + cnt_b + bsum_b);  // E*48 B

    int nscan = (N + 1023) / 1024;

    detect_dtype_kernel<<<1, 1, 0, stream>>>(node_attr, flag);
    prep_kernel<<<64, 256, 0, stream>>>(Wfc1, Wfc2, Wl20, Wl21, flag, w1t, w2t, w20t, w21t);
    (void)hipMemsetAsync(cnt, 0, (size_t)N * 4, stream);
    (void)hipMemsetAsync(agg, 0, agg_b, stream);

    // counting sort of edges by dst, materializing sorted 48 B records
    hist_kernel<<<(E + 255) / 256, 256, 0, stream>>>(edge_dst, cnt, E);
    scanA_kernel<<<nscan, 1024, 0, stream>>>(cnt, bsum, N);
    scanB_kernel<<<1, 64, 0, stream>>>(bsum, nscan);
    scanC_kernel<<<nscan, 1024, 0, stream>>>(cnt, bsum, N);
    scatter_build_kernel<<<(E + 255) / 256, 256, 0, stream>>>(
        edge_dst, edge_src, edge_attr, ele, flag, cnt, rec, E);

    node_y_kernel<<<(N + 15) / 16, 256, 0, stream>>>(node_input, node_attr, Wl10, Wl11, flag, y, N);

    fused_edge_kernel<<<(E + 63) / 64, 256, 0, stream>>>(
        rec, cnt, y, w1t, w2t, w20t, w21t, agg, E);

    out_kernel<<<(N + 15) / 16, 256, 0, stream>>>(node_input, node_attr, Wsc0, Wsc1,
                                                  agg, flag, d_out, N);
}

// Round 9
// 611.066 us; speedup vs baseline: 3.3670x; 1.0513x over previous
//
#include <hip/hip_runtime.h>
#include <hip/hip_bf16.h>

#define MUL 32
#define F4 128
#define NB 10
#define NH 100
#define EROW 136   // LDS row stride (ushorts) for sHW/sFeat: 272 B = 17*16, 16B-aligned rows
#define REC 48     // bytes/record: src@0, dst@4, ele bf16[10]@8, pad, ea f32[4]@32

#define INV_SQRT32 0.17677669529663687f
#define INV_SQRT10 0.31622776601683794f
#define INV_SQRT100 0.1f
#define INV_SQRT3 0.5773502691896258f
#define AGG_SCALE 0.25f   // 1/sqrt(16)
#define INV8 0.125f       // 1/sqrt(64)
#define C_S 0.3826834323650898f
#define C_X 0.9238795325112867f

typedef __attribute__((ext_vector_type(8))) short short8;
typedef __attribute__((ext_vector_type(4))) float float4v;

__device__ __forceinline__ float bf2f(__hip_bfloat16 v) { return __bfloat162float(v); }
__device__ __forceinline__ unsigned short f2b(float x) {
    __hip_bfloat16 b = __float2bfloat16(x);
    return *(unsigned short*)&b;
}
__device__ __forceinline__ float b2f(unsigned short u) {
    __hip_bfloat16 b;
    *(unsigned short*)&b = u;
    return __bfloat162float(b);
}
// flag: 1 = inputs fp32, 0 = inputs bf16
__device__ __forceinline__ float ldin(const void* p, size_t i, int f) {
    return f ? ((const float*)p)[i] : bf2f(((const __hip_bfloat16*)p)[i]);
}

// ---------------------------------------------------------------------------
__global__ void detect_dtype_kernel(const void* __restrict__ node_attr, int* __restrict__ flag) {
    unsigned w = *(const unsigned*)node_attr;
    *flag = (w == 0x3F800000u) ? 1 : 0;
}

// ---------------------------------------------------------------------------
// prep: k-contiguous bf16 B-operands. Parallel across 64 blocks.
// ---------------------------------------------------------------------------
__global__ __launch_bounds__(256) void prep_kernel(
    const void* __restrict__ Wfc1,   // 10 x 100
    const void* __restrict__ Wfc2,   // 100 x 128
    const void* __restrict__ Wl20,   // 64 x 32
    const void* __restrict__ Wl21,   // 64 x 32
    const int* __restrict__ flagp,
    unsigned short* __restrict__ w1t,
    unsigned short* __restrict__ w2t,
    unsigned short* __restrict__ w20t,
    unsigned short* __restrict__ w21t)
{
    int f = *flagp;
    int gi = blockIdx.x * 256 + threadIdx.x;
    if (gi < 128 * 128) {
        int n = gi >> 7, k = gi & 127;
        w2t[gi] = (k < NH) ? f2b(ldin(Wfc2, (size_t)k * 128 + n, f)) : 0;
    }
    if (gi < 32 * 64) {
        int v = gi >> 6, u = gi & 63;
        w20t[gi] = f2b(ldin(Wl20, (size_t)u * 32 + v, f));
        w21t[gi] = f2b(ldin(Wl21, (size_t)u * 32 + v, f));
    }
    if (gi < 112 * 32) {
        int n = gi >> 5, k = gi & 31;
        w1t[gi] = (k < NB && n < NH) ? f2b(ldin(Wfc1, (size_t)k * NH + n, f)) : 0;
    }
}

// ---------------------------------------------------------------------------
// Counting sort of edges by dst: hist -> 3-phase scan -> scatter_build.
// After scatter_build, cnt[n] = END offset of bucket n.
// ---------------------------------------------------------------------------
__global__ __launch_bounds__(256) void hist_kernel(
    const int* __restrict__ edst, int* __restrict__ cnt, int E)
{
    int i = blockIdx.x * 256 + threadIdx.x;
    if (i < E) atomicAdd(&cnt[edst[i]], 1);
}

// phase A: per-block exclusive scan of 1024-elem chunk; block total -> bsum
__global__ __launch_bounds__(1024) void scanA_kernel(
    int* __restrict__ cnt, int* __restrict__ bsum, int N)
{
    __shared__ int wsum[16];
    int t = threadIdx.x, lane = t & 63, wid = t >> 6;
    int i = blockIdx.x * 1024 + t;
    int v = (i < N) ? cnt[i] : 0;
    int x = v;
#pragma unroll
    for (int d = 1; d < 64; d <<= 1) { int yv = __shfl_up(x, d); if (lane >= d) x += yv; }
    if (lane == 63) wsum[wid] = x;
    __syncthreads();
    if (wid == 0 && lane < 16) {
        int s = wsum[lane];
#pragma unroll
        for (int d = 1; d < 16; d <<= 1) { int yv = __shfl_up(s, d); if (lane >= d) s += yv; }
        wsum[lane] = s;
    }
    __syncthreads();
    int pre = (wid > 0 ? wsum[wid - 1] : 0);
    if (i < N) cnt[i] = pre + x - v;          // exclusive within chunk
    if (t == 0) bsum[blockIdx.x] = wsum[15];  // chunk total
}

// phase B: single-wave exclusive scan of block totals
__global__ __launch_bounds__(64) void scanB_kernel(int* __restrict__ bsum, int nb)
{
    int t = threadIdx.x;
    int carry = 0;
    for (int c0 = 0; c0 < nb; c0 += 64) {
        int idx = c0 + t;
        int v = (idx < nb) ? bsum[idx] : 0;
        int x = v;
#pragma unroll
        for (int d = 1; d < 64; d <<= 1) { int yv = __shfl_up(x, d); if (t >= d) x += yv; }
        if (idx < nb) bsum[idx] = carry + x - v;
        carry += __shfl(x, 63);
    }
}

// phase C: add chunk offsets
__global__ __launch_bounds__(1024) void scanC_kernel(
    int* __restrict__ cnt, const int* __restrict__ bsum, int N)
{
    int i = blockIdx.x * 1024 + threadIdx.x;
    if (i < N) cnt[i] += bsum[blockIdx.x];
}

// scatter_build: coalesced reads of all per-edge inputs; one scattered 48 B
// record write at the edge's dst-sorted position.
__global__ __launch_bounds__(256) void scatter_build_kernel(
    const int* __restrict__ edst,
    const int* __restrict__ esrc,
    const void* __restrict__ eattr,  // E x 4
    const void* __restrict__ ele,    // E x 10
    const int* __restrict__ flagp,
    int* __restrict__ cnt,
    unsigned char* __restrict__ rec, int E)
{
    int i = blockIdx.x * 256 + threadIdx.x;
    if (i >= E) return;
    int f = *flagp;
    int d = edst[i];
    int p = atomicAdd(&cnt[d], 1);

    unsigned e0 = f2b(ldin(ele, (size_t)i * NB + 0, f));
    unsigned e1 = f2b(ldin(ele, (size_t)i * NB + 1, f));
    unsigned e2 = f2b(ldin(ele, (size_t)i * NB + 2, f));
    unsigned e3 = f2b(ldin(ele, (size_t)i * NB + 3, f));
    unsigned e4 = f2b(ldin(ele, (size_t)i * NB + 4, f));
    unsigned e5 = f2b(ldin(ele, (size_t)i * NB + 5, f));
    unsigned e6 = f2b(ldin(ele, (size_t)i * NB + 6, f));
    unsigned e7 = f2b(ldin(ele, (size_t)i * NB + 7, f));
    unsigned e8 = f2b(ldin(ele, (size_t)i * NB + 8, f));
    unsigned e9 = f2b(ldin(ele, (size_t)i * NB + 9, f));
    float ea0 = ldin(eattr, (size_t)i * 4 + 0, f);
    float ea1 = ldin(eattr, (size_t)i * 4 + 1, f);
    float ea2 = ldin(eattr, (size_t)i * 4 + 2, f);
    float ea3 = ldin(eattr, (size_t)i * 4 + 3, f);

    unsigned char* r = rec + (size_t)p * REC;
    *(int4*)(r + 0)  = make_int4(esrc[i], d, (int)(e0 | (e1 << 16)), (int)(e2 | (e3 << 16)));
    *(int4*)(r + 16) = make_int4((int)(e4 | (e5 << 16)), (int)(e6 | (e7 << 16)), (int)(e8 | (e9 << 16)), 0);
    *(float4*)(r + 32) = make_float4(ea0, ea1, ea2, ea3);
}

// ---------------------------------------------------------------------------
// node_y: y = fctp(x, attr, W_l10, W_l11) -> bf16 [N,128] PLANAR:
// y[n] = [ y0(32) | y1_d0(u:32) | y1_d1(32) | y1_d2(32) ]
// ---------------------------------------------------------------------------
__global__ __launch_bounds__(256) void node_y_kernel(
    const void* __restrict__ node_input,
    const void* __restrict__ node_attr,
    const void* __restrict__ Wl10,
    const void* __restrict__ Wl11,
    const int* __restrict__ flagp,
    unsigned short* __restrict__ y, int N)
{
    __shared__ float sW0[1024];
    __shared__ float sW1[1024];
    __shared__ float sX[16 * 128];
    int f = *flagp;
    int t = threadIdx.x;
    for (int i = t; i < 1024; i += 256) {
        sW0[i] = ldin(Wl10, i, f);
        sW1[i] = ldin(Wl11, i, f);
    }
    int n0 = blockIdx.x * 16;
    for (int i = t; i < 2048; i += 256) {
        int ln = i >> 7, c = i & 127, n = n0 + ln;
        sX[i] = (n < N) ? ldin(node_input, (size_t)n * F4 + c, f) : 0.f;
    }
    __syncthreads();
    for (int i = t; i < 2048; i += 256) {
        int ln = i >> 7, c = i & 127, n = n0 + ln;
        if (n >= N) continue;
        float attr = ldin(node_attr, n, f);
        float acc = 0.f;
        if (c < 32) {
#pragma unroll
            for (int u = 0; u < 32; u++) acc += sX[ln * 128 + u] * sW0[u * 32 + c];
        } else {
            int d = (c - 32) >> 5, u0 = (c - 32) & 31;
#pragma unroll
            for (int u = 0; u < 32; u++) acc += sX[ln * 128 + 32 + u * 3 + d] * sW1[u * 32 + u0];
        }
        y[(size_t)n * F4 + c] = f2b(acc * attr * INV_SQRT32);
    }
}

// ---------------------------------------------------------------------------
// Fused edge kernel over dst-sorted records: ONE fixed 64-edge tile per block.
// (256,6): 6 blocks/CU — round-8 was latency-bound at 4 blocks/CU (Occ 38%,
// nothing saturated). VGPR usage 52 < cap 85, so no spill expected; WRITE_SIZE
// is the spill litmus (must stay ~31 MB).
// src loads per-thread direct from rec (no sSrc LDS round-trip) so the y-row
// gather issues before the staging barrier and drains under P1/P2.
// ---------------------------------------------------------------------------
#define SM_ELEB  0        // ushort[64*32]   4096
#define SM_HW    4096     // ushort[64*136] 17408
#define SM_EA    21504    // float[64*4]     1024
#define SM_DST   22528    // int[64]          256
#define SM_TOTAL 22784    // x7 LDS-fits; bound gives 6 blocks/CU

__global__ __launch_bounds__(256, 6) void fused_edge_kernel(
    const unsigned char* __restrict__ rec,    // E x 48, dst-sorted records
    const int* __restrict__ cnt,              // N bucket END offsets
    const unsigned short* __restrict__ y,     // N x 128 bf16 planar
    const unsigned short* __restrict__ w1t,   // 112 x 32
    const unsigned short* __restrict__ w2t,   // 128 x 128
    const unsigned short* __restrict__ w20t,  // 32 x 64
    const unsigned short* __restrict__ w21t,  // 32 x 64
    float* __restrict__ agg,                  // N x 128 fp32 (memset 0)
    int E)
{
    __shared__ __align__(16) char smem[SM_TOTAL];
    unsigned short* sEleB = (unsigned short*)(smem + SM_ELEB);
    unsigned short* sHW = (unsigned short*)(smem + SM_HW);
    float* sEa = (float*)(smem + SM_EA);
    int* sDst = (int*)(smem + SM_DST);

    int t = threadIdx.x;
    int base = blockIdx.x * 64;
    int ne = E - base;
    if (ne > 64) ne = 64;

    int w = t >> 6, lane = t & 63;
    int lm = lane & 15, quad = lane >> 4;
    int em = w * 16 + lm;

    // ---- src direct load + y row gather: issued before any barrier ----
    int src = (em < ne) ? *(const int*)(rec + (size_t)(base + em) * REC) : 0;
    const unsigned short* yrg = y + (size_t)src * 128;
    short8 x0  = *(const short8*)(yrg + quad * 8);
    short8 xd0 = *(const short8*)(yrg + 32 + quad * 8);
    short8 xd1 = *(const short8*)(yrg + 64 + quad * 8);
    short8 xd2 = *(const short8*)(yrg + 96 + quad * 8);

    // ---- stage from sorted records (sequential ~3 KB region) ----
    if (t < 64)
        sDst[t] = (t < ne) ? *(const int*)(rec + (size_t)(base + t) * REC + 4) : -1;
    for (int i = t; i < 64 * 32; i += 256) {
        int e = i >> 5, k = i & 31;
        unsigned short v = 0;
        if (k < NB && e < ne)
            v = *(const unsigned short*)(rec + (size_t)(base + e) * REC + 8 + 2 * k);
        sEleB[i] = v;
    }
    {
        int e = t >> 2;
        sEa[t] = (e < ne) ? *(const float*)(rec + (size_t)(base + e) * REC + 32 + 4 * (t & 3)) : 0.f;
    }
    __syncthreads();

    // ---- P1: GEMM1 + silu -> sHW (single live accumulator) ----
    {
        short8 a = *(const short8*)(sEleB + (w * 16 + lm) * 32 + quad * 8);
#pragma unroll
        for (int nt = 0; nt < 7; nt++) {
            float4v c1 = (float4v){0.f, 0.f, 0.f, 0.f};
            short8 b = *(const short8*)(w1t + (nt * 16 + lm) * 32 + quad * 8);
            c1 = __builtin_amdgcn_mfma_f32_16x16x32_bf16(a, b, c1, 0, 0, 0);
            int ch = nt * 16 + lm;
#pragma unroll
            for (int r = 0; r < 4; r++) {
                int row = w * 16 + quad * 4 + r;
                float hv = 0.f;
                if (ch < NH) {
                    float aa = c1[r] * INV_SQRT10;
                    hv = aa / (1.f + __expf(-aa));
                }
                sHW[row * EROW + ch] = f2b(hv);
            }
        }
        // zero k in [112,128)
        int e = t >> 2, seg = t & 3;
        *(uint2*)(sHW + e * EROW + 112 + seg * 4) = (uint2){0u, 0u};
    }
    __syncthreads();

    // ---- P2: GEMM2, nt-outer single accumulator ----
    short8 hfr[4];
#pragma unroll
    for (int kc = 0; kc < 4; kc++)
        hfr[kc] = *(const short8*)(sHW + (w * 16 + lm) * EROW + kc * 32 + quad * 8);
    __syncthreads();
#pragma unroll
    for (int nt = 0; nt < 8; nt++) {
        float4v c2 = (float4v){0.f, 0.f, 0.f, 0.f};
#pragma unroll
        for (int kc = 0; kc < 4; kc++) {
            short8 b = *(const short8*)(w2t + (nt * 16 + lm) * 128 + kc * 32 + quad * 8);
            c2 = __builtin_amdgcn_mfma_f32_16x16x32_bf16(hfr[kc], b, c2, 0, 0, 0);
        }
#pragma unroll
        for (int r = 0; r < 4; r++)
            sHW[(w * 16 + quad * 4 + r) * EROW + nt * 16 + lm] = f2b(c2[r] * INV_SQRT100);
    }
    __syncthreads();

    // ---- PC: fragment build, barrier, then MFMA -> sFeat direct ----
    {
        const unsigned short* wr = sHW + em * EROW;
        short8 wA = *(const short8*)(wr + quad * 8);
        short8 wB = *(const short8*)(wr + 32 + quad * 8);
        short8 wC = *(const short8*)(wr + 64 + quad * 8);
        short8 wD = *(const short8*)(wr + 96 + quad * 8);
        float ea0 = sEa[em * 4 + 0];
        float e1x = sEa[em * 4 + 1];
        float e1y = sEa[em * 4 + 2];
        float e1z = sEa[em * 4 + 3];
        float ea0S = ea0 * AGG_SCALE;
        float s3 = AGG_SCALE * INV_SQRT3;

        short8 f00, f01, f10, f11, f20, f21, f30, f31;
#pragma unroll
        for (int j = 0; j < 8; j++) {
            float x0f = b2f((unsigned short)x0[j]);
            float d0f = b2f((unsigned short)xd0[j]);
            float d1f = b2f((unsigned short)xd1[j]);
            float d2f = b2f((unsigned short)xd2[j]);
            f00[j] = (short)f2b(b2f((unsigned short)wA[j]) * x0f * ea0S);
            float tt = d0f * e1x + d1f * e1y + d2f * e1z;
            f01[j] = (short)f2b(b2f((unsigned short)wD[j]) * tt * s3);
            float p = b2f((unsigned short)wB[j]) * x0f * AGG_SCALE;
            f10[j] = (short)f2b(p * e1x);
            f20[j] = (short)f2b(p * e1y);
            f30[j] = (short)f2b(p * e1z);
            float q = b2f((unsigned short)wC[j]) * ea0S;
            f11[j] = (short)f2b(q * d0f);
            f21[j] = (short)f2b(q * d1f);
            f31[j] = (short)f2b(q * d2f);
        }

        // all sHW/sEleB reads complete -> overlay becomes writable.
        // MFMA results stream straight to sFeat: no acc array crosses this barrier.
        __syncthreads();
        unsigned short* sFeat = (unsigned short*)smem;   // [64][EROW]
#pragma unroll
        for (int g = 0; g < 4; g++) {
            const unsigned short* wt = g ? w21t : w20t;
            short8 ak0 = (g == 0) ? f00 : (g == 1) ? f10 : (g == 2) ? f20 : f30;
            short8 ak1 = (g == 0) ? f01 : (g == 1) ? f11 : (g == 2) ? f21 : f31;
#pragma unroll
            for (int nt = 0; nt < 2; nt++) {
                float4v acc = (float4v){0.f, 0.f, 0.f, 0.f};
                short8 b0 = *(const short8*)(wt + (nt * 16 + lm) * 64 + quad * 8);
                short8 b1 = *(const short8*)(wt + (nt * 16 + lm) * 64 + 32 + quad * 8);
                acc = __builtin_amdgcn_mfma_f32_16x16x32_bf16(ak0, b0, acc, 0, 0, 0);
                acc = __builtin_amdgcn_mfma_f32_16x16x32_bf16(ak1, b1, acc, 0, 0, 0);
                int ch = (g == 0) ? (nt * 16 + lm) : (32 + (g - 1) * 32 + nt * 16 + lm);
#pragma unroll
                for (int r = 0; r < 4; r++) {
                    int er = w * 16 + quad * 4 + r;
                    sFeat[er * EROW + ch] = f2b(acc[r]);
                }
            }
        }
        __syncthreads();

        // ---- segmented run reduction: interior runs -> plain store;
        //      tile-edge-crossing runs -> atomicAdd. One thread per channel. ----
        if (t < 128) {
            int c = t;
            int e = 0;
            while (e < ne) {
                int d = sDst[e];           // uniform across the 128 threads
                int rs = e;
                do { e++; } while (e < ne && sDst[e] == d);
                if (d < 0) continue;
                float s = 0.f;
                for (int q = rs; q < e; q++) s += b2f(sFeat[q * EROW + c]);
                int bs = (d > 0) ? cnt[d - 1] : 0;   // bucket start
                int be = cnt[d];                     // bucket end
                if (bs >= base && be <= base + ne)
                    agg[(size_t)d * F4 + c] = s;     // exclusive owner
                else
                    atomicAdd(&agg[(size_t)d * F4 + c], s);
            }
        }
    }
}

// ---------------------------------------------------------------------------
// out: out = attr*(c_s * sc(x) + c_x * agg * INV8); 16 nodes/block
// agg layout: c<32 -> z0[c]; z1[u][d] at 32 + d*32 + u
// ---------------------------------------------------------------------------
__global__ __launch_bounds__(256) void out_kernel(
    const void* __restrict__ node_input,
    const void* __restrict__ node_attr,
    const void* __restrict__ Wsc0,
    const void* __restrict__ Wsc1,
    const float* __restrict__ agg,   // N x 128
    const int* __restrict__ flagp,
    void* __restrict__ out, int N)
{
    __shared__ float sWs0[1024], sWs1[1024];
    __shared__ float sX[16 * 128];
    __shared__ float sA[16 * 128];
    int f = *flagp;
    int t = threadIdx.x;
    for (int i = t; i < 1024; i += 256) {
        sWs0[i] = ldin(Wsc0, i, f);
        sWs1[i] = ldin(Wsc1, i, f);
    }
    int n0 = blockIdx.x * 16;
    for (int i = t; i < 2048; i += 256) {
        int ln = i >> 7, c = i & 127, n = n0 + ln;
        sX[i] = (n < N) ? ldin(node_input, (size_t)n * F4 + c, f) : 0.f;
        sA[i] = (n < N) ? agg[(size_t)n * F4 + c] : 0.f;
    }
    __syncthreads();
    for (int i = t; i < 2048; i += 256) {
        int ln = i >> 7, c = i & 127, n = n0 + ln;
        if (n >= N) continue;
        float attr = ldin(node_attr, n, f);
        float s, z;
        if (c < 32) {
            float as = 0.f;
#pragma unroll
            for (int u = 0; u < 32; u++) as += sX[ln * 128 + u] * sWs0[u * 32 + c];
            s = as * INV_SQRT32;
            z = sA[ln * 128 + c];
        } else {
            int i2 = c - 32;
            int u0 = i2 / 3, d = i2 - u0 * 3;
            float as = 0.f;
#pragma unroll
            for (int u = 0; u < 32; u++) as += sX[ln * 128 + 32 + u * 3 + d] * sWs1[u * 32 + u0];
            s = as * INV_SQRT32;
            z = sA[ln * 128 + 32 + d * 32 + u0];
        }
        float val = attr * (C_S * s + C_X * z * INV8);
        size_t oi = (size_t)n * F4 + c;
        if (f) ((float*)out)[oi] = val;
        else   ((__hip_bfloat16*)out)[oi] = __float2bfloat16(val);
    }
}

// ---------------------------------------------------------------------------
extern "C" void kernel_launch(void* const* d_in, const int* in_sizes, int n_in,
                              void* d_out, int out_size, void* d_ws, size_t ws_size,
                              hipStream_t stream) {
    const void* node_input = d_in[0];
    const void* node_attr  = d_in[1];
    const int* edge_src    = (const int*)d_in[2];
    const int* edge_dst    = (const int*)d_in[3];
    const void* edge_attr  = d_in[4];
    const void* ele        = d_in[5];
    const void* Wsc0       = d_in[6];
    const void* Wsc1       = d_in[7];
    const void* Wl10       = d_in[8];
    const void* Wl11       = d_in[9];
    const void* Wl20       = d_in[10];
    const void* Wl21       = d_in[11];
    const void* Wfc1       = d_in[12];
    const void* Wfc2       = d_in[13];

    int N = in_sizes[0] / F4;   // 50000
    int E = in_sizes[2];        // 800000

    char* ws = (char*)d_ws;
    int* flag = (int*)ws;                                        // 64 B
    unsigned short* y = (unsigned short*)(ws + 64);              // N*128 bf16
    size_t y_b = (size_t)N * F4 * 2;
    float* agg = (float*)(ws + 64 + y_b);                        // N*128 fp32
    size_t agg_b = (size_t)N * F4 * 4;
    size_t off = 64 + y_b + agg_b;
    unsigned short* w2t  = (unsigned short*)(ws + off);          // 32 KB
    unsigned short* w20t = (unsigned short*)(ws + off + 32768);  // 4 KB
    unsigned short* w21t = (unsigned short*)(ws + off + 36864);  // 4 KB
    unsigned short* w1t  = (unsigned short*)(ws + off + 40960);  // 7 KB
    size_t off2 = off + 49152;
    int* cnt = (int*)(ws + off2);                                // N ints
    size_t cnt_b = ((size_t)N * 4 + 63) & ~(size_t)63;
    int* bsum = (int*)(ws + off2 + cnt_b);                       // scan block sums
    size_t bsum_b = 4096;
    unsigned char* rec = (unsigned char*)(ws + off2 + cnt_b + bsum_b);  // E*48 B

    int nscan = (N + 1023) / 1024;

    detect_dtype_kernel<<<1, 1, 0, stream>>>(node_attr, flag);
    prep_kernel<<<64, 256, 0, stream>>>(Wfc1, Wfc2, Wl20, Wl21, flag, w1t, w2t, w20t, w21t);
    (void)hipMemsetAsync(cnt, 0, (size_t)N * 4, stream);
    (void)hipMemsetAsync(agg, 0, agg_b, stream);

    // counting sort of edges by dst, materializing sorted 48 B records
    hist_kernel<<<(E + 255) / 256, 256, 0, stream>>>(edge_dst, cnt, E);
    scanA_kernel<<<nscan, 1024, 0, stream>>>(cnt, bsum, N);
    scanB_kernel<<<1, 64, 0, stream>>>(bsum, nscan);
    scanC_kernel<<<nscan, 1024, 0, stream>>>(cnt, bsum, N);
    scatter_build_kernel<<<(E + 255) / 256, 256, 0, stream>>>(
        edge_dst, edge_src, edge_attr, ele, flag, cnt, rec, E);

    node_y_kernel<<<(N + 15) / 16, 256, 0, stream>>>(node_input, node_attr, Wl10, Wl11, flag, y, N);

    fused_edge_kernel<<<(E + 63) / 64, 256, 0, stream>>>(
        rec, cnt, y, w1t, w2t, w20t, w21t, agg, E);

    out_kernel<<<(N + 15) / 16, 256, 0, stream>>>(node_input, node_attr, Wsc0, Wsc1,
                                                  agg, flag, d_out, N);
}